// Round 10
// baseline (1057.803 us; speedup 1.0000x reference)
//
#include <hip/hip_runtime.h>
#include <hip/hip_bf16.h>

constexpr int B    = 16;
constexpr int N    = 4096;
constexpr int CIN  = 64;
constexpr int COUT = 128;
constexpr int M    = 1024;
constexpr int K    = 32;

constexpr int K1  = 96;   // layer-1 MFMA K: 64 x + 3 rel + 29 zero pad
constexpr int LDH = 136;  // A2 row stride (pad +8)
constexpr int NCONS = 240;
constexpr int PUBM  = 15; // publish progress when (t & 15) == 15

typedef __attribute__((ext_vector_type(8))) short short8;
typedef __attribute__((ext_vector_type(4))) float f32x4;
typedef __attribute__((ext_vector_type(2))) float f32x2;

// RNE float->bf16 (finite values)
static __device__ __forceinline__ unsigned short f2bf(float f) {
  unsigned u = __float_as_uint(f);
  unsigned r = (u + 0x7FFFu + ((u >> 16) & 1u)) >> 16;
  return (unsigned short)r;
}

// fast mish: v * tanh(softplus(v)) == v * s/(s+2), s = u^2+2u, u = e^v
static __device__ __forceinline__ float fast_mish(float v) {
  float u = __expf(v);
  float s = u * (u + 2.0f);
  float t = s / (s + 2.0f);
  return (v > 60.f) ? v : v * t;
}

// ---------------------------------------------------------------------------
// Wave-wide u32 max via DPP (row_shr 1/2/4/8, row_bcast 15/31, readlane 63).
// ---------------------------------------------------------------------------
template <int CTRL, int RM>
static __device__ __forceinline__ unsigned dpp_umax_step(unsigned x) {
  int o = __builtin_amdgcn_update_dpp((int)x, (int)x, CTRL, RM, 0xF, false);
  unsigned u = (unsigned)o;
  return x > u ? x : u;
}
static __device__ __forceinline__ unsigned wave_umax(unsigned x) {
  x = dpp_umax_step<0x111, 0xF>(x);  // row_shr:1
  x = dpp_umax_step<0x112, 0xF>(x);  // row_shr:2
  x = dpp_umax_step<0x114, 0xF>(x);  // row_shr:4
  x = dpp_umax_step<0x118, 0xF>(x);  // row_shr:8
  x = dpp_umax_step<0x142, 0xA>(x);  // row_bcast:15 -> rows 1,3
  x = dpp_umax_step<0x143, 0xC>(x);  // row_bcast:31 -> rows 2,3
  return (unsigned)__builtin_amdgcn_readlane((int)x, 63);
}

static __device__ __forceinline__ unsigned long long umax64(unsigned long long a,
                                                            unsigned long long b) {
  return a > b ? a : b;
}

// ---------------------------------------------------------------------------
// Weight prep: W1t[n][k] = bf16(W1[k][n]) for k<67 else 0   (n<128, k<96)
//              W2t[n][k] = bf16(W2[k][n])                   (n<128, k<128)
// ---------------------------------------------------------------------------
__global__ __launch_bounds__(256) void prep_weights(const float* __restrict__ W1,
                                                    const float* __restrict__ W2,
                                                    unsigned short* __restrict__ W1t,
                                                    unsigned short* __restrict__ W2t) {
  const int n = blockIdx.x;    // 128
  const int t = threadIdx.x;   // 256
  if (t < K1) {
    W1t[n * K1 + t] = (t < 67) ? f2bf(W1[t * 128 + n]) : (unsigned short)0;
  } else if (t < K1 + 128) {
    int k = t - K1;
    W2t[n * 128 + k] = f2bf(W2[k * 128 + n]);
  }
}

// ---------------------------------------------------------------------------
// MEGA kernel, grid = 256 blocks x 512 threads (1 block/CU, all co-resident).
// Blocks 0..15:   FPS producer for cloud b (= fps8 structure, unchanged math)
//                 + agent-release progress[b] publish every 16 selections.
// Blocks 16..255: consumer waves; wave -> centroid W, W+1920, ... (b-major:
//                 a block's 8 waves share one cloud). Spin (acquire) on
//                 progress, then fused KNN (winners captured to n0/n1 regs,
//                 no nbr buffer) + barrier-free wave-per-centroid MFMA MLP.
// ---------------------------------------------------------------------------
__global__ __launch_bounds__(512) void mega_kernel(
    const float* __restrict__ x, const float* __restrict__ pos,
    const unsigned short* __restrict__ W1t, const unsigned short* __restrict__ W2t,
    const float* __restrict__ b1, const float* __restrict__ b2,
    const float* __restrict__ Wlin, const float* __restrict__ blin,
    int* __restrict__ idx, int* __restrict__ progress, float* __restrict__ pos4,
    float* __restrict__ xout, float* __restrict__ pout) {
  __shared__ __align__(16) unsigned char smem[69760];
  const int tid = threadIdx.x;

  if (blockIdx.x < B) {
    // ======================= FPS producer =======================
#pragma clang fp contract(off)
    const int b = blockIdx.x;
    float(*sp)[4] = (float(*)[4])smem;                                     // 64 KB
    unsigned long long(*skey)[8] = (unsigned long long(*)[8])(smem + 65536);
    const float* p = pos + (size_t)b * (N * 3);
    float* p4 = pos4 + (size_t)b * N * 4;

    f32x2 px2[4], py2[4], pz2[4];
    float mind[8];
#pragma unroll
    for (int j = 0; j < 8; j++) {
      const int n = tid + j * 512;
      const float xx = p[3 * n + 0];
      const float yy = p[3 * n + 1];
      const float zz = p[3 * n + 2];
      px2[j >> 1][j & 1] = xx;
      py2[j >> 1][j & 1] = yy;
      pz2[j >> 1][j & 1] = zz;
      mind[j] = __builtin_inff();
      f32x4 v;
      v[0] = xx; v[1] = yy; v[2] = zz; v[3] = 0.f;
      *(f32x4*)(&sp[n][0]) = v;
      *(f32x4*)(p4 + 4 * n) = v;
    }
    float qx = p[0], qy = p[1], qz = p[2];
    if (tid == 0) {
      idx[b * M + 0] = 0;
      pout[(size_t)(b * M + 0) * 3 + 0] = qx;
      pout[(size_t)(b * M + 0) * 3 + 1] = qy;
      pout[(size_t)(b * M + 0) * 3 + 2] = qz;
    }
    __syncthreads();  // drains all threads' pos4/sp stores (vmcnt+lgkm)

    const int wv = tid >> 6, lane = tid & 63;
    for (int t = 1; t < M; t++) {
      const f32x2 nqx = {-qx, -qx};
      const f32x2 nqy = {-qy, -qy};
      const f32x2 nqz = {-qz, -qz};
      float bv = -1.f;
      unsigned bn = 0;
#pragma unroll
      for (int k = 0; k < 4; k++) {
        f32x2 dx = px2[k] + nqx;                  // v_pk_add_f32 (exact sub)
        f32x2 dy = py2[k] + nqy;
        f32x2 dz = pz2[k] + nqz;
        f32x2 s = (dx * dx + dy * dy) + dz * dz;  // numpy order, no fma
        const float mi0 = fminf(mind[2 * k + 0], s.x);
        mind[2 * k + 0] = mi0;
        bool c0 = mi0 > bv;  // strict >, ascending n: smallest index on ties
        bv = c0 ? mi0 : bv;
        bn = c0 ? (unsigned)(tid + (2 * k + 0) * 512) : bn;
        const float mi1 = fminf(mind[2 * k + 1], s.y);
        mind[2 * k + 1] = mi1;
        bool c1 = mi1 > bv;
        bv = c1 ? mi1 : bv;
        bn = c1 ? (unsigned)(tid + (2 * k + 1) * 512) : bn;
      }
      const unsigned vb = __float_as_uint(bv);  // nonneg floats: monotone bits
      const unsigned wb = wave_umax(vb);        // wave max value
      unsigned tk = (vb == wb) ? ~bn : 0u;
      tk = wave_umax(tk);                       // ties -> smallest n
      const int par = t & 1;
      if (lane == 0) skey[par][wv] = ((unsigned long long)wb << 32) | tk;
      __syncthreads();
      const unsigned long long k0 = skey[par][0];
      const unsigned long long k1 = skey[par][1];
      const unsigned long long k2 = skey[par][2];
      const unsigned long long k3 = skey[par][3];
      const unsigned long long k4 = skey[par][4];
      const unsigned long long k5 = skey[par][5];
      const unsigned long long k6 = skey[par][6];
      const unsigned long long k7 = skey[par][7];
      const unsigned long long bb =
          umax64(umax64(umax64(k0, k1), umax64(k2, k3)),
                 umax64(umax64(k4, k5), umax64(k6, k7)));
      const unsigned n = ~(unsigned)bb;
      const f32x4 qv = *(const f32x4*)(&sp[n][0]);  // one dependent b128 read
      qx = qv[0];
      qy = qv[1];
      qz = qv[2];
      if (tid == 0) {
        idx[b * M + t] = (int)n;
        pout[(size_t)(b * M + t) * 3 + 0] = qx;
        pout[(size_t)(b * M + t) * 3 + 1] = qy;
        pout[(size_t)(b * M + t) * 3 + 2] = qz;
        if ((t & PUBM) == PUBM) {
          // release: drains this thread's idx/pout stores + wbl2 makes the
          // whole block's prior writes (barrier-ordered) agent-visible.
          __hip_atomic_store(progress + b, t + 1, __ATOMIC_RELEASE,
                             __HIP_MEMORY_SCOPE_AGENT);
        }
      }
    }
  } else {
    // ======================= consumer: KNN + MLP =======================
    const int wv = tid >> 6, lane = tid & 63;
    const int lrow = lane & 15;
    const int g = lane >> 4;
    unsigned short* A2 = (unsigned short*)smem + wv * (32 * LDH);
    const int wgid = (blockIdx.x - B) * 8 + wv;

    for (int W = wgid; W < B * M; W += NCONS * 8) {
      const int b = W >> 10;
      const int t = W & (M - 1);
      // spin until this centroid's idx is published (acquire orders the
      // dependent idx/pos4 reads; first-run poison is negative -> waits;
      // replay-stale pass reads bit-identical data)
      int got = __hip_atomic_load(progress + b, __ATOMIC_ACQUIRE,
                                  __HIP_MEMORY_SCOPE_AGENT);
      while (got <= t) {
        __builtin_amdgcn_s_sleep(8);
        got = __hip_atomic_load(progress + b, __ATOMIC_ACQUIRE,
                                __HIP_MEMORY_SCOPE_AGENT);
      }
      const float* p4 = pos4 + (size_t)b * N * 4;
      const int sel = idx[W];
      const f32x4 q = *(const f32x4*)(p4 + 4 * sel);
      int n0 = 0, n1 = 0;
      {
#pragma clang fp contract(off)
        const f32x2 nqx = {-q[0], -q[0]};
        const f32x2 nqy = {-q[1], -q[1]};
        const f32x2 nqz = {-q[2], -q[2]};
        float d[64];
#pragma unroll
        for (int jj = 0; jj < 32; jj++) {
          const f32x4 v0 = *(const f32x4*)(p4 + 4 * ((2 * jj + 0) * 64 + lane));
          const f32x4 v1 = *(const f32x4*)(p4 + 4 * ((2 * jj + 1) * 64 + lane));
          f32x2 vx = {v0[0], v1[0]};
          f32x2 vy = {v0[1], v1[1]};
          f32x2 vz = {v0[2], v1[2]};
          f32x2 dx = vx + nqx;
          f32x2 dy = vy + nqy;
          f32x2 dz = vz + nqz;
          f32x2 s = (dx * dx + dy * dy) + dz * dz;  // numpy order, exact
          d[2 * jj + 0] = s.x;
          d[2 * jj + 1] = s.y;
        }
        float gv[8];
        int gj[8];
#pragma unroll
        for (int gg = 0; gg < 8; gg++) {
          gv[gg] = __builtin_inff();
          gj[gg] = 8 * gg;
#pragma unroll
          for (int e = 0; e < 8; e++) {
            const int j = 8 * gg + e;
            bool c = d[j] < gv[gg];
            gv[gg] = c ? d[j] : gv[gg];
            gj[gg] = c ? j : gj[gg];
          }
        }
        for (int r = 0; r < K; r++) {
          float bv = __builtin_inff();
          int bj = 0;
#pragma unroll
          for (int gg = 0; gg < 8; gg++) {
            bool c = gv[gg] < bv;
            bv = c ? gv[gg] : bv;
            bj = c ? gj[gg] : bj;
          }
          const unsigned bn = (unsigned)(bj * 64 + lane);
          const unsigned nb = ~__float_as_uint(bv);  // ~bits: umax -> min dist
          const unsigned wnb = wave_umax(nb);
          unsigned tk = (nb == wnb) ? (0xFFFFFFFFu - bn) : 0u;
          tk = wave_umax(tk);                        // ties -> smallest n
          const unsigned wn = 0xFFFFFFFFu - tk;      // uniform across wave
          n0 = (r == lrow) ? (int)wn : n0;           // capture for MLP
          n1 = (r == 16 + lrow) ? (int)wn : n1;
          const int wj = (int)(wn >> 6);
          const int wl = (int)(wn & 63);
          const int wg = wj >> 3;
#pragma unroll
          for (int gg = 0; gg < 8; gg++) {
            if (gg == wg) {  // scalar-uniform: only winner's group pays
#pragma unroll
              for (int e = 0; e < 8; e++) {
                if (8 * gg + e == wj) {
                  if (lane == wl) d[8 * gg + e] = __builtin_inff();
                }
              }
              float nv = __builtin_inff();
              int nj = 8 * gg;
#pragma unroll
              for (int e = 0; e < 8; e++) {
                const int j = 8 * gg + e;
                bool c = d[j] < nv;
                nv = c ? d[j] : nv;
                nj = c ? j : nj;
              }
              gv[gg] = nv;
              gj[gg] = nj;
            }
          }
        }
      }

      // ---------------- MLP (barrier-free, wave-private A2) ----------------
      const float qx = q[0], qy = q[1], qz = q[2];
      short8 a0[3], a1[3];
      {
        const float* xr0 = x + ((size_t)b * N + n0) * CIN;
        const float* xr1 = x + ((size_t)b * N + n1) * CIN;
#pragma unroll
        for (int kc = 0; kc < 2; kc++) {
          const int k0 = kc * 32 + g * 8;
          f32x4 u0 = *(const f32x4*)(xr0 + k0);
          f32x4 u1 = *(const f32x4*)(xr0 + k0 + 4);
          f32x4 v0 = *(const f32x4*)(xr1 + k0);
          f32x4 v1 = *(const f32x4*)(xr1 + k0 + 4);
          short8 ha, hb;
#pragma unroll
          for (int e = 0; e < 4; e++) {
            ha[e] = (short)f2bf(u0[e]);
            ha[e + 4] = (short)f2bf(u1[e]);
            hb[e] = (short)f2bf(v0[e]);
            hb[e + 4] = (short)f2bf(v1[e]);
          }
          a0[kc] = ha;
          a1[kc] = hb;
        }
        short8 z = {};
        a0[2] = z;
        a1[2] = z;
        if (g == 0) {  // k = 64..71: {rel.x, rel.y, rel.z, 0...}
          float r0x = p4[4 * n0 + 0] - qx, r0y = p4[4 * n0 + 1] - qy, r0z = p4[4 * n0 + 2] - qz;
          float r1x = p4[4 * n1 + 0] - qx, r1y = p4[4 * n1 + 1] - qy, r1z = p4[4 * n1 + 2] - qz;
          a0[2][0] = (short)f2bf(r0x); a0[2][1] = (short)f2bf(r0y); a0[2][2] = (short)f2bf(r0z);
          a1[2][0] = (short)f2bf(r1x); a1[2][1] = (short)f2bf(r1y); a1[2][2] = (short)f2bf(r1z);
        }
      }

      // layer 1: C1[32,128] = A1 @ W1t^T, mish -> A2 (wave-private)
#pragma unroll 2
      for (int nt = 0; nt < 8; nt++) {
        const unsigned short* w1r = W1t + (size_t)(nt * 16 + lrow) * K1 + g * 8;
        f32x4 c0 = {}, c1 = {};
#pragma unroll
        for (int kc = 0; kc < 3; kc++) {
          short8 bfr = *(const short8*)(w1r + kc * 32);
          c0 = __builtin_amdgcn_mfma_f32_16x16x32_bf16(a0[kc], bfr, c0, 0, 0, 0);
          c1 = __builtin_amdgcn_mfma_f32_16x16x32_bf16(a1[kc], bfr, c1, 0, 0, 0);
        }
        const int colI = nt * 16 + lrow;
        const float bb = b1[colI];
#pragma unroll
        for (int reg = 0; reg < 4; reg++) {
          const int row = g * 4 + reg;  // C layout (m89): col=lane&15, row=(lane>>4)*4+reg
          A2[row * LDH + colI] = f2bf(fast_mish(c0[reg] + bb));
          A2[(16 + row) * LDH + colI] = f2bf(fast_mish(c1[reg] + bb));
        }
      }

      f32x4 xq[4];
      {
        const float* xs = x + ((size_t)b * N + sel) * CIN + g * 16;
#pragma unroll
        for (int v = 0; v < 4; v++) xq[v] = *(const f32x4*)(xs + 4 * v);
      }

      // layer 2 + max over 32 rows + epilogue (in-wave LDS ordering: DS ops
      // from one wave execute in order; compiler inserts lgkmcnt waits)
#pragma unroll 2
      for (int nt = 0; nt < 8; nt++) {
        const unsigned short* w2r = W2t + (size_t)(nt * 16 + lrow) * 128 + g * 8;
        f32x4 c0 = {}, c1 = {};
#pragma unroll
        for (int kc = 0; kc < 4; kc++) {
          short8 af0 = *(const short8*)(A2 + lrow * LDH + kc * 32 + g * 8);
          short8 af1 = *(const short8*)(A2 + (16 + lrow) * LDH + kc * 32 + g * 8);
          short8 bfr = *(const short8*)(w2r + kc * 32);
          c0 = __builtin_amdgcn_mfma_f32_16x16x32_bf16(af0, bfr, c0, 0, 0, 0);
          c1 = __builtin_amdgcn_mfma_f32_16x16x32_bf16(af1, bfr, c1, 0, 0, 0);
        }
        float pm = fmaxf(fmaxf(fmaxf(c0[0], c0[1]), fmaxf(c0[2], c0[3])),
                         fmaxf(fmaxf(c1[0], c1[1]), fmaxf(c1[2], c1[3])));
        pm = fmaxf(pm, __shfl_xor(pm, 16, 64));
        pm = fmaxf(pm, __shfl_xor(pm, 32, 64));  // max over all 32 rows, col j
        const int j = nt * 16 + lrow;
        float s = 0.f;
#pragma unroll
        for (int e = 0; e < 16; e++) {
          s += xq[e >> 2][e & 3] * Wlin[(g * 16 + e) * 128 + j];
        }
        s += __shfl_xor(s, 16, 64);
        s += __shfl_xor(s, 32, 64);  // full 64-k dot
        if (g == 0) {
          xout[(size_t)W * 128 + j] = pm + b2[j] + s + blin[j];
        }
      }
    }
  }
}

// ---------------------------------------------------------------------------
extern "C" void kernel_launch(void* const* d_in, const int* in_sizes, int n_in,
                              void* d_out, int out_size, void* d_ws, size_t ws_size,
                              hipStream_t stream) {
  const float* x    = (const float*)d_in[0];
  const float* pos  = (const float*)d_in[1];
  const float* W1   = (const float*)d_in[2];
  const float* b1   = (const float*)d_in[3];
  const float* W2   = (const float*)d_in[4];
  const float* b2   = (const float*)d_in[5];
  const float* Wlin = (const float*)d_in[6];
  const float* blin = (const float*)d_in[7];

  float* out  = (float*)d_out;                 // float32 outputs
  float* xout = out;                           // [B*M*COUT]
  float* pout = out + (size_t)B * M * COUT;    // [B*M*3]

  char* ws = (char*)d_ws;
  int* idx            = (int*)ws;                           // 64 KB
  int* progress       = (int*)(ws + 65536);                 // 256 B (16 used)
  unsigned short* W1t = (unsigned short*)(ws + 65792);      // 24 KB
  unsigned short* W2t = (unsigned short*)(ws + 90368);      // 32 KB
  float* pos4         = (float*)(ws + 123136);              // 1 MB

  prep_weights<<<dim3(128), dim3(256), 0, stream>>>(W1, W2, W1t, W2t);
  mega_kernel<<<dim3(B + NCONS), dim3(512), 0, stream>>>(
      x, pos, W1t, W2t, b1, b2, Wlin, blin, idx, progress, pos4, xout, pout);
}

// Round 11
// 1057.183 us; speedup vs baseline: 1.0006x; 1.0006x over previous
//
#include <hip/hip_runtime.h>
#include <hip/hip_bf16.h>

constexpr int B    = 16;
constexpr int N    = 4096;
constexpr int CIN  = 64;
constexpr int COUT = 128;
constexpr int M    = 1024;
constexpr int K    = 32;

constexpr int K1  = 96;   // layer-1 MFMA K: 64 x + 3 rel + 29 zero pad
constexpr int LDH = 136;  // A2 row stride (pad +8)
constexpr int NCONS = 240;
constexpr int PUBM  = 15; // publish progress when (t & 15) == 15

typedef __attribute__((ext_vector_type(8))) short short8;
typedef __attribute__((ext_vector_type(4))) float f32x4;
typedef __attribute__((ext_vector_type(2))) float f32x2;

// RNE float->bf16 (finite values)
static __device__ __forceinline__ unsigned short f2bf(float f) {
  unsigned u = __float_as_uint(f);
  unsigned r = (u + 0x7FFFu + ((u >> 16) & 1u)) >> 16;
  return (unsigned short)r;
}

// fast mish: v * tanh(softplus(v)) == v * s/(s+2), s = u^2+2u, u = e^v
static __device__ __forceinline__ float fast_mish(float v) {
  float u = __expf(v);
  float s = u * (u + 2.0f);
  float t = s / (s + 2.0f);
  return (v > 60.f) ? v : v * t;
}

// ---------------------------------------------------------------------------
// Wave-wide u32 max via DPP (row_shr 1/2/4/8, row_bcast 15/31, readlane 63).
// ---------------------------------------------------------------------------
template <int CTRL, int RM>
static __device__ __forceinline__ unsigned dpp_umax_step(unsigned x) {
  int o = __builtin_amdgcn_update_dpp((int)x, (int)x, CTRL, RM, 0xF, false);
  unsigned u = (unsigned)o;
  return x > u ? x : u;
}
static __device__ __forceinline__ unsigned wave_umax(unsigned x) {
  x = dpp_umax_step<0x111, 0xF>(x);  // row_shr:1
  x = dpp_umax_step<0x112, 0xF>(x);  // row_shr:2
  x = dpp_umax_step<0x114, 0xF>(x);  // row_shr:4
  x = dpp_umax_step<0x118, 0xF>(x);  // row_shr:8
  x = dpp_umax_step<0x142, 0xA>(x);  // row_bcast:15 -> rows 1,3
  x = dpp_umax_step<0x143, 0xC>(x);  // row_bcast:31 -> rows 2,3
  return (unsigned)__builtin_amdgcn_readlane((int)x, 63);
}

static __device__ __forceinline__ unsigned long long umax64(unsigned long long a,
                                                            unsigned long long b) {
  return a > b ? a : b;
}

// ---------------------------------------------------------------------------
// Weight prep: W1t[n][k] = bf16(W1[k][n]) for k<67 else 0   (n<128, k<96)
//              W2t[n][k] = bf16(W2[k][n])                   (n<128, k<128)
// ---------------------------------------------------------------------------
__global__ __launch_bounds__(256) void prep_weights(const float* __restrict__ W1,
                                                    const float* __restrict__ W2,
                                                    unsigned short* __restrict__ W1t,
                                                    unsigned short* __restrict__ W2t) {
  const int n = blockIdx.x;    // 128
  const int t = threadIdx.x;   // 256
  if (t < K1) {
    W1t[n * K1 + t] = (t < 67) ? f2bf(W1[t * 128 + n]) : (unsigned short)0;
  } else if (t < K1 + 128) {
    int k = t - K1;
    W2t[n * 128 + k] = f2bf(W2[k * 128 + n]);
  }
}

// ---------------------------------------------------------------------------
// MEGA kernel, grid = 256 blocks x 512 threads. LDS padded to 86016 B so
// 2 blocks/CU CANNOT fit (2x86016 > 163840) -> exactly 1 block/CU, all 256
// co-resident, producers on dedicated CUs (round-10 packed 2/CU and
// serialized producer issue with consumers -> 1123 us).
// Blocks 0..15:   FPS producer for cloud b + agent-release progress publish
//                 every 16 selections.
// Blocks 16..255: consumer waves; wave -> centroid W, W+1920, ... (b-major:
//                 a block's 8 waves share one cloud). Spin (acquire) on
//                 progress, then fused KNN (winners to n0/n1 regs, no nbr
//                 buffer) + barrier-free wave-per-centroid MFMA MLP.
// ---------------------------------------------------------------------------
__global__ __launch_bounds__(512) void mega_kernel(
    const float* __restrict__ x, const float* __restrict__ pos,
    const unsigned short* __restrict__ W1t, const unsigned short* __restrict__ W2t,
    const float* __restrict__ b1, const float* __restrict__ b2,
    const float* __restrict__ Wlin, const float* __restrict__ blin,
    int* __restrict__ idx, int* __restrict__ progress, float* __restrict__ pos4,
    float* __restrict__ xout, float* __restrict__ pout) {
  __shared__ __align__(16) unsigned char smem[86016];  // > 80KB: 1 block/CU
  const int tid = threadIdx.x;

  if (blockIdx.x < B) {
    // ======================= FPS producer =======================
#pragma clang fp contract(off)
    const int b = blockIdx.x;
    float(*sp)[4] = (float(*)[4])smem;                                     // 64 KB
    unsigned long long(*skey)[8] = (unsigned long long(*)[8])(smem + 65536);
    const float* p = pos + (size_t)b * (N * 3);
    float* p4 = pos4 + (size_t)b * N * 4;

    f32x2 px2[4], py2[4], pz2[4];
    float mind[8];
#pragma unroll
    for (int j = 0; j < 8; j++) {
      const int n = tid + j * 512;
      const float xx = p[3 * n + 0];
      const float yy = p[3 * n + 1];
      const float zz = p[3 * n + 2];
      px2[j >> 1][j & 1] = xx;
      py2[j >> 1][j & 1] = yy;
      pz2[j >> 1][j & 1] = zz;
      mind[j] = __builtin_inff();
      f32x4 v;
      v[0] = xx; v[1] = yy; v[2] = zz; v[3] = 0.f;
      *(f32x4*)(&sp[n][0]) = v;
      *(f32x4*)(p4 + 4 * n) = v;
    }
    float qx = p[0], qy = p[1], qz = p[2];
    if (tid == 0) {
      idx[b * M + 0] = 0;
      pout[(size_t)(b * M + 0) * 3 + 0] = qx;
      pout[(size_t)(b * M + 0) * 3 + 1] = qy;
      pout[(size_t)(b * M + 0) * 3 + 2] = qz;
    }
    __syncthreads();  // drains all threads' pos4/sp stores (vmcnt+lgkm)

    const int wv = tid >> 6, lane = tid & 63;
    for (int t = 1; t < M; t++) {
      const f32x2 nqx = {-qx, -qx};
      const f32x2 nqy = {-qy, -qy};
      const f32x2 nqz = {-qz, -qz};
      float bv = -1.f;
      unsigned bn = 0;
#pragma unroll
      for (int k = 0; k < 4; k++) {
        f32x2 dx = px2[k] + nqx;                  // v_pk_add_f32 (exact sub)
        f32x2 dy = py2[k] + nqy;
        f32x2 dz = pz2[k] + nqz;
        f32x2 s = (dx * dx + dy * dy) + dz * dz;  // numpy order, no fma
        const float mi0 = fminf(mind[2 * k + 0], s.x);
        mind[2 * k + 0] = mi0;
        bool c0 = mi0 > bv;  // strict >, ascending n: smallest index on ties
        bv = c0 ? mi0 : bv;
        bn = c0 ? (unsigned)(tid + (2 * k + 0) * 512) : bn;
        const float mi1 = fminf(mind[2 * k + 1], s.y);
        mind[2 * k + 1] = mi1;
        bool c1 = mi1 > bv;
        bv = c1 ? mi1 : bv;
        bn = c1 ? (unsigned)(tid + (2 * k + 1) * 512) : bn;
      }
      const unsigned vb = __float_as_uint(bv);  // nonneg floats: monotone bits
      const unsigned wb = wave_umax(vb);        // wave max value
      unsigned tk = (vb == wb) ? ~bn : 0u;
      tk = wave_umax(tk);                       // ties -> smallest n
      const int par = t & 1;
      if (lane == 0) skey[par][wv] = ((unsigned long long)wb << 32) | tk;
      __syncthreads();
      const unsigned long long k0 = skey[par][0];
      const unsigned long long k1 = skey[par][1];
      const unsigned long long k2 = skey[par][2];
      const unsigned long long k3 = skey[par][3];
      const unsigned long long k4 = skey[par][4];
      const unsigned long long k5 = skey[par][5];
      const unsigned long long k6 = skey[par][6];
      const unsigned long long k7 = skey[par][7];
      const unsigned long long bb =
          umax64(umax64(umax64(k0, k1), umax64(k2, k3)),
                 umax64(umax64(k4, k5), umax64(k6, k7)));
      const unsigned n = ~(unsigned)bb;
      const f32x4 qv = *(const f32x4*)(&sp[n][0]);  // one dependent b128 read
      qx = qv[0];
      qy = qv[1];
      qz = qv[2];
      if (tid == 0) {
        idx[b * M + t] = (int)n;
        pout[(size_t)(b * M + t) * 3 + 0] = qx;
        pout[(size_t)(b * M + t) * 3 + 1] = qy;
        pout[(size_t)(b * M + t) * 3 + 2] = qz;
        if ((t & PUBM) == PUBM) {
          // release: drains this thread's idx/pout stores + wbl2 makes the
          // whole block's prior writes (barrier-ordered) agent-visible.
          __hip_atomic_store(progress + b, t + 1, __ATOMIC_RELEASE,
                             __HIP_MEMORY_SCOPE_AGENT);
        }
      }
    }
  } else {
    // ======================= consumer: KNN + MLP =======================
    const int wv = tid >> 6, lane = tid & 63;
    const int lrow = lane & 15;
    const int g = lane >> 4;
    unsigned short* A2 = (unsigned short*)smem + wv * (32 * LDH);
    const int wgid = (blockIdx.x - B) * 8 + wv;

    for (int W = wgid; W < B * M; W += NCONS * 8) {
      const int b = W >> 10;
      const int t = W & (M - 1);
      // spin until this centroid's idx is published (acquire orders the
      // dependent idx/pos4 reads; first-run poison is negative -> waits;
      // replay-stale pass reads bit-identical data)
      int got = __hip_atomic_load(progress + b, __ATOMIC_ACQUIRE,
                                  __HIP_MEMORY_SCOPE_AGENT);
      while (got <= t) {
        __builtin_amdgcn_s_sleep(8);
        got = __hip_atomic_load(progress + b, __ATOMIC_ACQUIRE,
                                __HIP_MEMORY_SCOPE_AGENT);
      }
      const float* p4 = pos4 + (size_t)b * N * 4;
      const int sel = idx[W];
      const f32x4 q = *(const f32x4*)(p4 + 4 * sel);
      int n0 = 0, n1 = 0;
      {
#pragma clang fp contract(off)
        const f32x2 nqx = {-q[0], -q[0]};
        const f32x2 nqy = {-q[1], -q[1]};
        const f32x2 nqz = {-q[2], -q[2]};
        float d[64];
#pragma unroll
        for (int jj = 0; jj < 32; jj++) {
          const f32x4 v0 = *(const f32x4*)(p4 + 4 * ((2 * jj + 0) * 64 + lane));
          const f32x4 v1 = *(const f32x4*)(p4 + 4 * ((2 * jj + 1) * 64 + lane));
          f32x2 vx = {v0[0], v1[0]};
          f32x2 vy = {v0[1], v1[1]};
          f32x2 vz = {v0[2], v1[2]};
          f32x2 dx = vx + nqx;
          f32x2 dy = vy + nqy;
          f32x2 dz = vz + nqz;
          f32x2 s = (dx * dx + dy * dy) + dz * dz;  // numpy order, exact
          d[2 * jj + 0] = s.x;
          d[2 * jj + 1] = s.y;
        }
        float gv[8];
        int gj[8];
#pragma unroll
        for (int gg = 0; gg < 8; gg++) {
          gv[gg] = __builtin_inff();
          gj[gg] = 8 * gg;
#pragma unroll
          for (int e = 0; e < 8; e++) {
            const int j = 8 * gg + e;
            bool c = d[j] < gv[gg];
            gv[gg] = c ? d[j] : gv[gg];
            gj[gg] = c ? j : gj[gg];
          }
        }
        for (int r = 0; r < K; r++) {
          float bv = __builtin_inff();
          int bj = 0;
#pragma unroll
          for (int gg = 0; gg < 8; gg++) {
            bool c = gv[gg] < bv;
            bv = c ? gv[gg] : bv;
            bj = c ? gj[gg] : bj;
          }
          const unsigned bn = (unsigned)(bj * 64 + lane);
          const unsigned nb = ~__float_as_uint(bv);  // ~bits: umax -> min dist
          const unsigned wnb = wave_umax(nb);
          unsigned tk = (nb == wnb) ? (0xFFFFFFFFu - bn) : 0u;
          tk = wave_umax(tk);                        // ties -> smallest n
          const unsigned wn = 0xFFFFFFFFu - tk;      // uniform across wave
          n0 = (r == lrow) ? (int)wn : n0;           // capture for MLP
          n1 = (r == 16 + lrow) ? (int)wn : n1;
          const int wj = (int)(wn >> 6);
          const int wl = (int)(wn & 63);
          const int wg = wj >> 3;
#pragma unroll
          for (int gg = 0; gg < 8; gg++) {
            if (gg == wg) {  // scalar-uniform: only winner's group pays
#pragma unroll
              for (int e = 0; e < 8; e++) {
                if (8 * gg + e == wj) {
                  if (lane == wl) d[8 * gg + e] = __builtin_inff();
                }
              }
              float nv = __builtin_inff();
              int nj = 8 * gg;
#pragma unroll
              for (int e = 0; e < 8; e++) {
                const int j = 8 * gg + e;
                bool c = d[j] < nv;
                nv = c ? d[j] : nv;
                nj = c ? j : nj;
              }
              gv[gg] = nv;
              gj[gg] = nj;
            }
          }
        }
      }

      // ---------------- MLP (barrier-free, wave-private A2) ----------------
      const float qx = q[0], qy = q[1], qz = q[2];
      short8 a0[3], a1[3];
      {
        const float* xr0 = x + ((size_t)b * N + n0) * CIN;
        const float* xr1 = x + ((size_t)b * N + n1) * CIN;
#pragma unroll
        for (int kc = 0; kc < 2; kc++) {
          const int k0 = kc * 32 + g * 8;
          f32x4 u0 = *(const f32x4*)(xr0 + k0);
          f32x4 u1 = *(const f32x4*)(xr0 + k0 + 4);
          f32x4 v0 = *(const f32x4*)(xr1 + k0);
          f32x4 v1 = *(const f32x4*)(xr1 + k0 + 4);
          short8 ha, hb;
#pragma unroll
          for (int e = 0; e < 4; e++) {
            ha[e] = (short)f2bf(u0[e]);
            ha[e + 4] = (short)f2bf(u1[e]);
            hb[e] = (short)f2bf(v0[e]);
            hb[e + 4] = (short)f2bf(v1[e]);
          }
          a0[kc] = ha;
          a1[kc] = hb;
        }
        short8 z = {};
        a0[2] = z;
        a1[2] = z;
        if (g == 0) {  // k = 64..71: {rel.x, rel.y, rel.z, 0...}
          float r0x = p4[4 * n0 + 0] - qx, r0y = p4[4 * n0 + 1] - qy, r0z = p4[4 * n0 + 2] - qz;
          float r1x = p4[4 * n1 + 0] - qx, r1y = p4[4 * n1 + 1] - qy, r1z = p4[4 * n1 + 2] - qz;
          a0[2][0] = (short)f2bf(r0x); a0[2][1] = (short)f2bf(r0y); a0[2][2] = (short)f2bf(r0z);
          a1[2][0] = (short)f2bf(r1x); a1[2][1] = (short)f2bf(r1y); a1[2][2] = (short)f2bf(r1z);
        }
      }

      // layer 1: C1[32,128] = A1 @ W1t^T, mish -> A2 (wave-private)
#pragma unroll 2
      for (int nt = 0; nt < 8; nt++) {
        const unsigned short* w1r = W1t + (size_t)(nt * 16 + lrow) * K1 + g * 8;
        f32x4 c0 = {}, c1 = {};
#pragma unroll
        for (int kc = 0; kc < 3; kc++) {
          short8 bfr = *(const short8*)(w1r + kc * 32);
          c0 = __builtin_amdgcn_mfma_f32_16x16x32_bf16(a0[kc], bfr, c0, 0, 0, 0);
          c1 = __builtin_amdgcn_mfma_f32_16x16x32_bf16(a1[kc], bfr, c1, 0, 0, 0);
        }
        const int colI = nt * 16 + lrow;
        const float bb = b1[colI];
#pragma unroll
        for (int reg = 0; reg < 4; reg++) {
          const int row = g * 4 + reg;  // C layout (m89): col=lane&15, row=(lane>>4)*4+reg
          A2[row * LDH + colI] = f2bf(fast_mish(c0[reg] + bb));
          A2[(16 + row) * LDH + colI] = f2bf(fast_mish(c1[reg] + bb));
        }
      }

      f32x4 xq[4];
      {
        const float* xs = x + ((size_t)b * N + sel) * CIN + g * 16;
#pragma unroll
        for (int v = 0; v < 4; v++) xq[v] = *(const f32x4*)(xs + 4 * v);
      }

      // layer 2 + max over 32 rows + epilogue (in-wave LDS ordering: DS ops
      // from one wave execute in order; compiler inserts lgkmcnt waits)
#pragma unroll 2
      for (int nt = 0; nt < 8; nt++) {
        const unsigned short* w2r = W2t + (size_t)(nt * 16 + lrow) * 128 + g * 8;
        f32x4 c0 = {}, c1 = {};
#pragma unroll
        for (int kc = 0; kc < 4; kc++) {
          short8 af0 = *(const short8*)(A2 + lrow * LDH + kc * 32 + g * 8);
          short8 af1 = *(const short8*)(A2 + (16 + lrow) * LDH + kc * 32 + g * 8);
          short8 bfr = *(const short8*)(w2r + kc * 32);
          c0 = __builtin_amdgcn_mfma_f32_16x16x32_bf16(af0, bfr, c0, 0, 0, 0);
          c1 = __builtin_amdgcn_mfma_f32_16x16x32_bf16(af1, bfr, c1, 0, 0, 0);
        }
        float pm = fmaxf(fmaxf(fmaxf(c0[0], c0[1]), fmaxf(c0[2], c0[3])),
                         fmaxf(fmaxf(c1[0], c1[1]), fmaxf(c1[2], c1[3])));
        pm = fmaxf(pm, __shfl_xor(pm, 16, 64));
        pm = fmaxf(pm, __shfl_xor(pm, 32, 64));  // max over all 32 rows, col j
        const int j = nt * 16 + lrow;
        float s = 0.f;
#pragma unroll
        for (int e = 0; e < 16; e++) {
          s += xq[e >> 2][e & 3] * Wlin[(g * 16 + e) * 128 + j];
        }
        s += __shfl_xor(s, 16, 64);
        s += __shfl_xor(s, 32, 64);  // full 64-k dot
        if (g == 0) {
          xout[(size_t)W * 128 + j] = pm + b2[j] + s + blin[j];
        }
      }
    }
  }
}

// ---------------------------------------------------------------------------
extern "C" void kernel_launch(void* const* d_in, const int* in_sizes, int n_in,
                              void* d_out, int out_size, void* d_ws, size_t ws_size,
                              hipStream_t stream) {
  const float* x    = (const float*)d_in[0];
  const float* pos  = (const float*)d_in[1];
  const float* W1   = (const float*)d_in[2];
  const float* b1   = (const float*)d_in[3];
  const float* W2   = (const float*)d_in[4];
  const float* b2   = (const float*)d_in[5];
  const float* Wlin = (const float*)d_in[6];
  const float* blin = (const float*)d_in[7];

  float* out  = (float*)d_out;                 // float32 outputs
  float* xout = out;                           // [B*M*COUT]
  float* pout = out + (size_t)B * M * COUT;    // [B*M*3]

  char* ws = (char*)d_ws;
  int* idx            = (int*)ws;                           // 64 KB
  int* progress       = (int*)(ws + 65536);                 // 256 B (16 used)
  unsigned short* W1t = (unsigned short*)(ws + 65792);      // 24 KB
  unsigned short* W2t = (unsigned short*)(ws + 90368);      // 32 KB
  float* pos4         = (float*)(ws + 123136);              // 1 MB

  prep_weights<<<dim3(128), dim3(256), 0, stream>>>(W1, W2, W1t, W2t);
  mega_kernel<<<dim3(B + NCONS), dim3(512), 0, stream>>>(
      x, pos, W1t, W2t, b1, b2, Wlin, blin, idx, progress, pos4, xout, pout);
}

// Round 12
// 966.642 us; speedup vs baseline: 1.0943x; 1.0937x over previous
//
#include <hip/hip_runtime.h>
#include <hip/hip_bf16.h>

constexpr int B    = 16;
constexpr int N    = 4096;
constexpr int CIN  = 64;
constexpr int COUT = 128;
constexpr int M    = 1024;
constexpr int K    = 32;

constexpr int K1  = 96;   // layer-1 MFMA K: 64 x + 3 rel + 29 zero pad
constexpr int LDH = 136;  // A2 row stride (pad +8)
constexpr int NCONS = 240;
constexpr int PUBM  = 15;  // publish progress when (t & 15) == 15
constexpr int PSTRIDE = 32;  // progress: one 128B line per cloud

typedef __attribute__((ext_vector_type(8))) short short8;
typedef __attribute__((ext_vector_type(4))) float f32x4;
typedef __attribute__((ext_vector_type(2))) float f32x2;

// RNE float->bf16 (finite values)
static __device__ __forceinline__ unsigned short f2bf(float f) {
  unsigned u = __float_as_uint(f);
  unsigned r = (u + 0x7FFFu + ((u >> 16) & 1u)) >> 16;
  return (unsigned short)r;
}

// fast mish: v * tanh(softplus(v)) == v * s/(s+2), s = u^2+2u, u = e^v
static __device__ __forceinline__ float fast_mish(float v) {
  float u = __expf(v);
  float s = u * (u + 2.0f);
  float t = s / (s + 2.0f);
  return (v > 60.f) ? v : v * t;
}

// ---------------------------------------------------------------------------
// Wave-wide u32 max via DPP (row_shr 1/2/4/8, row_bcast 15/31, readlane 63).
// ---------------------------------------------------------------------------
template <int CTRL, int RM>
static __device__ __forceinline__ unsigned dpp_umax_step(unsigned x) {
  int o = __builtin_amdgcn_update_dpp((int)x, (int)x, CTRL, RM, 0xF, false);
  unsigned u = (unsigned)o;
  return x > u ? x : u;
}
static __device__ __forceinline__ unsigned wave_umax(unsigned x) {
  x = dpp_umax_step<0x111, 0xF>(x);  // row_shr:1
  x = dpp_umax_step<0x112, 0xF>(x);  // row_shr:2
  x = dpp_umax_step<0x114, 0xF>(x);  // row_shr:4
  x = dpp_umax_step<0x118, 0xF>(x);  // row_shr:8
  x = dpp_umax_step<0x142, 0xA>(x);  // row_bcast:15 -> rows 1,3
  x = dpp_umax_step<0x143, 0xC>(x);  // row_bcast:31 -> rows 2,3
  return (unsigned)__builtin_amdgcn_readlane((int)x, 63);
}

static __device__ __forceinline__ unsigned long long umax64(unsigned long long a,
                                                            unsigned long long b) {
  return a > b ? a : b;
}

// ---------------------------------------------------------------------------
// Weight prep: W1t[n][k] = bf16(W1[k][n]) for k<67 else 0   (n<128, k<96)
//              W2t[n][k] = bf16(W2[k][n])                   (n<128, k<128)
// ---------------------------------------------------------------------------
__global__ __launch_bounds__(256) void prep_weights(const float* __restrict__ W1,
                                                    const float* __restrict__ W2,
                                                    unsigned short* __restrict__ W1t,
                                                    unsigned short* __restrict__ W2t) {
  const int n = blockIdx.x;    // 128
  const int t = threadIdx.x;   // 256
  if (t < K1) {
    W1t[n * K1 + t] = (t < 67) ? f2bf(W1[t * 128 + n]) : (unsigned short)0;
  } else if (t < K1 + 128) {
    int k = t - K1;
    W2t[n * 128 + k] = f2bf(W2[k * 128 + n]);
  }
}

// ---------------------------------------------------------------------------
// MEGA kernel, grid = 256 blocks x 512 threads, LDS 86016 -> 1 block/CU.
// Round-11 lesson: agent-RELEASE per publish emits buffer_wbl2 (full L2
// writeback, ~7us) on wave0's critical path -> +444us. Fix: shared scalars
// (idx/pout/progress) are written with RELAXED AGENT atomic stores (sc1,
// straight to the coherent point); publish = s_waitcnt vmcnt(0) + relaxed
// progress store (store-completion order). Only ONE release (with wbl2)
// after the bulk pos4 init. Consumers: relaxed polls (no buffer_inv),
// relaxed idx load (bypass stale L2); pos4/x static after the one release.
// ---------------------------------------------------------------------------
__global__ __launch_bounds__(512) void mega_kernel(
    const float* __restrict__ x, const float* __restrict__ pos,
    const unsigned short* __restrict__ W1t, const unsigned short* __restrict__ W2t,
    const float* __restrict__ b1, const float* __restrict__ b2,
    const float* __restrict__ Wlin, const float* __restrict__ blin,
    int* __restrict__ idx, int* __restrict__ progress, float* __restrict__ pos4,
    float* __restrict__ xout, float* __restrict__ pout) {
  __shared__ __align__(16) unsigned char smem[86016];  // > 80KB: 1 block/CU
  const int tid = threadIdx.x;

  if (blockIdx.x < B) {
    // ======================= FPS producer =======================
#pragma clang fp contract(off)
    const int b = blockIdx.x;
    float(*sp)[4] = (float(*)[4])smem;                                     // 64 KB
    unsigned long long(*skey)[8] = (unsigned long long(*)[8])(smem + 65536);
    const float* p = pos + (size_t)b * (N * 3);
    float* p4 = pos4 + (size_t)b * N * 4;

    f32x2 px2[4], py2[4], pz2[4];
    float mind[8];
#pragma unroll
    for (int j = 0; j < 8; j++) {
      const int n = tid + j * 512;
      const float xx = p[3 * n + 0];
      const float yy = p[3 * n + 1];
      const float zz = p[3 * n + 2];
      px2[j >> 1][j & 1] = xx;
      py2[j >> 1][j & 1] = yy;
      pz2[j >> 1][j & 1] = zz;
      mind[j] = __builtin_inff();
      f32x4 v;
      v[0] = xx; v[1] = yy; v[2] = zz; v[3] = 0.f;
      *(f32x4*)(&sp[n][0]) = v;
      *(f32x4*)(p4 + 4 * n) = v;
    }
    float qx = p[0], qy = p[1], qz = p[2];
    if (tid == 0) {
      __hip_atomic_store(idx + b * M, 0, __ATOMIC_RELAXED, __HIP_MEMORY_SCOPE_AGENT);
      __hip_atomic_store(pout + (size_t)(b * M) * 3 + 0, qx, __ATOMIC_RELAXED, __HIP_MEMORY_SCOPE_AGENT);
      __hip_atomic_store(pout + (size_t)(b * M) * 3 + 1, qy, __ATOMIC_RELAXED, __HIP_MEMORY_SCOPE_AGENT);
      __hip_atomic_store(pout + (size_t)(b * M) * 3 + 2, qz, __ATOMIC_RELAXED, __HIP_MEMORY_SCOPE_AGENT);
    }
    __syncthreads();  // all threads' pos4/sp stores drained (vmcnt+lgkm)
    if (tid == 0) {
      // ONE-TIME release: wbl2 pushes the block's pos4 L2 lines to the
      // coherent point; publishes centroid 0.
      __hip_atomic_store(progress + b * PSTRIDE, 1, __ATOMIC_RELEASE,
                         __HIP_MEMORY_SCOPE_AGENT);
    }

    const int wv = tid >> 6, lane = tid & 63;
    for (int t = 1; t < M; t++) {
      const f32x2 nqx = {-qx, -qx};
      const f32x2 nqy = {-qy, -qy};
      const f32x2 nqz = {-qz, -qz};
      float bv = -1.f;
      unsigned bn = 0;
#pragma unroll
      for (int k = 0; k < 4; k++) {
        f32x2 dx = px2[k] + nqx;                  // v_pk_add_f32 (exact sub)
        f32x2 dy = py2[k] + nqy;
        f32x2 dz = pz2[k] + nqz;
        f32x2 s = (dx * dx + dy * dy) + dz * dz;  // numpy order, no fma
        const float mi0 = fminf(mind[2 * k + 0], s.x);
        mind[2 * k + 0] = mi0;
        bool c0 = mi0 > bv;  // strict >, ascending n: smallest index on ties
        bv = c0 ? mi0 : bv;
        bn = c0 ? (unsigned)(tid + (2 * k + 0) * 512) : bn;
        const float mi1 = fminf(mind[2 * k + 1], s.y);
        mind[2 * k + 1] = mi1;
        bool c1 = mi1 > bv;
        bv = c1 ? mi1 : bv;
        bn = c1 ? (unsigned)(tid + (2 * k + 1) * 512) : bn;
      }
      const unsigned vb = __float_as_uint(bv);  // nonneg floats: monotone bits
      const unsigned wb = wave_umax(vb);        // wave max value
      unsigned tk = (vb == wb) ? ~bn : 0u;
      tk = wave_umax(tk);                       // ties -> smallest n
      const int par = t & 1;
      if (lane == 0) skey[par][wv] = ((unsigned long long)wb << 32) | tk;
      __syncthreads();
      const unsigned long long k0 = skey[par][0];
      const unsigned long long k1 = skey[par][1];
      const unsigned long long k2 = skey[par][2];
      const unsigned long long k3 = skey[par][3];
      const unsigned long long k4 = skey[par][4];
      const unsigned long long k5 = skey[par][5];
      const unsigned long long k6 = skey[par][6];
      const unsigned long long k7 = skey[par][7];
      const unsigned long long bb =
          umax64(umax64(umax64(k0, k1), umax64(k2, k3)),
                 umax64(umax64(k4, k5), umax64(k6, k7)));
      const unsigned n = ~(unsigned)bb;
      const f32x4 qv = *(const f32x4*)(&sp[n][0]);  // one dependent b128 read
      qx = qv[0];
      qy = qv[1];
      qz = qv[2];
      if (tid == 0) {
        __hip_atomic_store(idx + b * M + t, (int)n, __ATOMIC_RELAXED, __HIP_MEMORY_SCOPE_AGENT);
        __hip_atomic_store(pout + (size_t)(b * M + t) * 3 + 0, qx, __ATOMIC_RELAXED, __HIP_MEMORY_SCOPE_AGENT);
        __hip_atomic_store(pout + (size_t)(b * M + t) * 3 + 1, qy, __ATOMIC_RELAXED, __HIP_MEMORY_SCOPE_AGENT);
        __hip_atomic_store(pout + (size_t)(b * M + t) * 3 + 2, qz, __ATOMIC_RELAXED, __HIP_MEMORY_SCOPE_AGENT);
        if ((t & PUBM) == PUBM) {
          // drain tid0's sc1 stores to the coherent point, then publish.
          asm volatile("s_waitcnt vmcnt(0)" ::: "memory");
          __hip_atomic_store(progress + b * PSTRIDE, t + 1, __ATOMIC_RELAXED,
                             __HIP_MEMORY_SCOPE_AGENT);
        }
      }
    }
  } else {
    // ======================= consumer: KNN + MLP =======================
    const int wv = tid >> 6, lane = tid & 63;
    const int lrow = lane & 15;
    const int g = lane >> 4;
    unsigned short* A2 = (unsigned short*)smem + wv * (32 * LDH);
    const int wgid = (blockIdx.x - B) * 8 + wv;

    for (int W = wgid; W < B * M; W += NCONS * 8) {
      const int b = W >> 10;
      const int t = W & (M - 1);
      // relaxed polls (no cache maintenance); first-run poison is negative
      // -> waits; replay-stale 1024 -> sprints into bit-identical data.
      int got = __hip_atomic_load(progress + b * PSTRIDE, __ATOMIC_RELAXED,
                                  __HIP_MEMORY_SCOPE_AGENT);
      while (got <= t) {
        __builtin_amdgcn_s_sleep(64);
        got = __hip_atomic_load(progress + b * PSTRIDE, __ATOMIC_RELAXED,
                                __HIP_MEMORY_SCOPE_AGENT);
      }
      const float* p4 = pos4 + (size_t)b * N * 4;
      // idx line may be stale in this XCD's L2 -> sc1 load (coherent point)
      const int sel = __hip_atomic_load(idx + W, __ATOMIC_RELAXED,
                                        __HIP_MEMORY_SCOPE_AGENT);
      const f32x4 q = *(const f32x4*)(p4 + 4 * sel);
      int n0 = 0, n1 = 0;
      {
#pragma clang fp contract(off)
        const f32x2 nqx = {-q[0], -q[0]};
        const f32x2 nqy = {-q[1], -q[1]};
        const f32x2 nqz = {-q[2], -q[2]};
        float d[64];
#pragma unroll
        for (int jj = 0; jj < 32; jj++) {
          const f32x4 v0 = *(const f32x4*)(p4 + 4 * ((2 * jj + 0) * 64 + lane));
          const f32x4 v1 = *(const f32x4*)(p4 + 4 * ((2 * jj + 1) * 64 + lane));
          f32x2 vx = {v0[0], v1[0]};
          f32x2 vy = {v0[1], v1[1]};
          f32x2 vz = {v0[2], v1[2]};
          f32x2 dx = vx + nqx;
          f32x2 dy = vy + nqy;
          f32x2 dz = vz + nqz;
          f32x2 s = (dx * dx + dy * dy) + dz * dz;  // numpy order, exact
          d[2 * jj + 0] = s.x;
          d[2 * jj + 1] = s.y;
        }
        float gv[8];
        int gj[8];
#pragma unroll
        for (int gg = 0; gg < 8; gg++) {
          gv[gg] = __builtin_inff();
          gj[gg] = 8 * gg;
#pragma unroll
          for (int e = 0; e < 8; e++) {
            const int j = 8 * gg + e;
            bool c = d[j] < gv[gg];
            gv[gg] = c ? d[j] : gv[gg];
            gj[gg] = c ? j : gj[gg];
          }
        }
        for (int r = 0; r < K; r++) {
          float bv = __builtin_inff();
          int bj = 0;
#pragma unroll
          for (int gg = 0; gg < 8; gg++) {
            bool c = gv[gg] < bv;
            bv = c ? gv[gg] : bv;
            bj = c ? gj[gg] : bj;
          }
          const unsigned bn = (unsigned)(bj * 64 + lane);
          const unsigned nb = ~__float_as_uint(bv);  // ~bits: umax -> min dist
          const unsigned wnb = wave_umax(nb);
          unsigned tk = (nb == wnb) ? (0xFFFFFFFFu - bn) : 0u;
          tk = wave_umax(tk);                        // ties -> smallest n
          const unsigned wn = 0xFFFFFFFFu - tk;      // uniform across wave
          n0 = (r == lrow) ? (int)wn : n0;           // capture for MLP
          n1 = (r == 16 + lrow) ? (int)wn : n1;
          const int wj = (int)(wn >> 6);
          const int wl = (int)(wn & 63);
          const int wg = wj >> 3;
#pragma unroll
          for (int gg = 0; gg < 8; gg++) {
            if (gg == wg) {  // scalar-uniform: only winner's group pays
#pragma unroll
              for (int e = 0; e < 8; e++) {
                if (8 * gg + e == wj) {
                  if (lane == wl) d[8 * gg + e] = __builtin_inff();
                }
              }
              float nv = __builtin_inff();
              int nj = 8 * gg;
#pragma unroll
              for (int e = 0; e < 8; e++) {
                const int j = 8 * gg + e;
                bool c = d[j] < nv;
                nv = c ? d[j] : nv;
                nj = c ? j : nj;
              }
              gv[gg] = nv;
              gj[gg] = nj;
            }
          }
        }
      }

      // ---------------- MLP (barrier-free, wave-private A2) ----------------
      const float qx = q[0], qy = q[1], qz = q[2];
      short8 a0[3], a1[3];
      {
        const float* xr0 = x + ((size_t)b * N + n0) * CIN;
        const float* xr1 = x + ((size_t)b * N + n1) * CIN;
#pragma unroll
        for (int kc = 0; kc < 2; kc++) {
          const int k0 = kc * 32 + g * 8;
          f32x4 u0 = *(const f32x4*)(xr0 + k0);
          f32x4 u1 = *(const f32x4*)(xr0 + k0 + 4);
          f32x4 v0 = *(const f32x4*)(xr1 + k0);
          f32x4 v1 = *(const f32x4*)(xr1 + k0 + 4);
          short8 ha, hb;
#pragma unroll
          for (int e = 0; e < 4; e++) {
            ha[e] = (short)f2bf(u0[e]);
            ha[e + 4] = (short)f2bf(u1[e]);
            hb[e] = (short)f2bf(v0[e]);
            hb[e + 4] = (short)f2bf(v1[e]);
          }
          a0[kc] = ha;
          a1[kc] = hb;
        }
        short8 z = {};
        a0[2] = z;
        a1[2] = z;
        if (g == 0) {  // k = 64..71: {rel.x, rel.y, rel.z, 0...}
          float r0x = p4[4 * n0 + 0] - qx, r0y = p4[4 * n0 + 1] - qy, r0z = p4[4 * n0 + 2] - qz;
          float r1x = p4[4 * n1 + 0] - qx, r1y = p4[4 * n1 + 1] - qy, r1z = p4[4 * n1 + 2] - qz;
          a0[2][0] = (short)f2bf(r0x); a0[2][1] = (short)f2bf(r0y); a0[2][2] = (short)f2bf(r0z);
          a1[2][0] = (short)f2bf(r1x); a1[2][1] = (short)f2bf(r1y); a1[2][2] = (short)f2bf(r1z);
        }
      }

      // layer 1: C1[32,128] = A1 @ W1t^T, mish -> A2 (wave-private)
#pragma unroll 2
      for (int nt = 0; nt < 8; nt++) {
        const unsigned short* w1r = W1t + (size_t)(nt * 16 + lrow) * K1 + g * 8;
        f32x4 c0 = {}, c1 = {};
#pragma unroll
        for (int kc = 0; kc < 3; kc++) {
          short8 bfr = *(const short8*)(w1r + kc * 32);
          c0 = __builtin_amdgcn_mfma_f32_16x16x32_bf16(a0[kc], bfr, c0, 0, 0, 0);
          c1 = __builtin_amdgcn_mfma_f32_16x16x32_bf16(a1[kc], bfr, c1, 0, 0, 0);
        }
        const int colI = nt * 16 + lrow;
        const float bb = b1[colI];
#pragma unroll
        for (int reg = 0; reg < 4; reg++) {
          const int row = g * 4 + reg;  // C layout (m89): col=lane&15, row=(lane>>4)*4+reg
          A2[row * LDH + colI] = f2bf(fast_mish(c0[reg] + bb));
          A2[(16 + row) * LDH + colI] = f2bf(fast_mish(c1[reg] + bb));
        }
      }

      f32x4 xq[4];
      {
        const float* xs = x + ((size_t)b * N + sel) * CIN + g * 16;
#pragma unroll
        for (int v = 0; v < 4; v++) xq[v] = *(const f32x4*)(xs + 4 * v);
      }

      // layer 2 + max over 32 rows + epilogue (in-wave LDS ordering)
#pragma unroll 2
      for (int nt = 0; nt < 8; nt++) {
        const unsigned short* w2r = W2t + (size_t)(nt * 16 + lrow) * 128 + g * 8;
        f32x4 c0 = {}, c1 = {};
#pragma unroll
        for (int kc = 0; kc < 4; kc++) {
          short8 af0 = *(const short8*)(A2 + lrow * LDH + kc * 32 + g * 8);
          short8 af1 = *(const short8*)(A2 + (16 + lrow) * LDH + kc * 32 + g * 8);
          short8 bfr = *(const short8*)(w2r + kc * 32);
          c0 = __builtin_amdgcn_mfma_f32_16x16x32_bf16(af0, bfr, c0, 0, 0, 0);
          c1 = __builtin_amdgcn_mfma_f32_16x16x32_bf16(af1, bfr, c1, 0, 0, 0);
        }
        float pm = fmaxf(fmaxf(fmaxf(c0[0], c0[1]), fmaxf(c0[2], c0[3])),
                         fmaxf(fmaxf(c1[0], c1[1]), fmaxf(c1[2], c1[3])));
        pm = fmaxf(pm, __shfl_xor(pm, 16, 64));
        pm = fmaxf(pm, __shfl_xor(pm, 32, 64));  // max over all 32 rows, col j
        const int j = nt * 16 + lrow;
        float s = 0.f;
#pragma unroll
        for (int e = 0; e < 16; e++) {
          s += xq[e >> 2][e & 3] * Wlin[(g * 16 + e) * 128 + j];
        }
        s += __shfl_xor(s, 16, 64);
        s += __shfl_xor(s, 32, 64);  // full 64-k dot
        if (g == 0) {
          xout[(size_t)W * 128 + j] = pm + b2[j] + s + blin[j];
        }
      }
    }
  }
}

// ---------------------------------------------------------------------------
extern "C" void kernel_launch(void* const* d_in, const int* in_sizes, int n_in,
                              void* d_out, int out_size, void* d_ws, size_t ws_size,
                              hipStream_t stream) {
  const float* x    = (const float*)d_in[0];
  const float* pos  = (const float*)d_in[1];
  const float* W1   = (const float*)d_in[2];
  const float* b1   = (const float*)d_in[3];
  const float* W2   = (const float*)d_in[4];
  const float* b2   = (const float*)d_in[5];
  const float* Wlin = (const float*)d_in[6];
  const float* blin = (const float*)d_in[7];

  float* out  = (float*)d_out;                 // float32 outputs
  float* xout = out;                           // [B*M*COUT]
  float* pout = out + (size_t)B * M * COUT;    // [B*M*3]

  char* ws = (char*)d_ws;
  int* idx            = (int*)ws;                           // 64 KB
  int* progress       = (int*)(ws + 65536);                 // 2 KB (16 lines)
  unsigned short* W1t = (unsigned short*)(ws + 67584);      // 24 KB
  unsigned short* W2t = (unsigned short*)(ws + 92160);      // 32 KB
  float* pos4         = (float*)(ws + 124928);              // 1 MB

  prep_weights<<<dim3(128), dim3(256), 0, stream>>>(W1, W2, W1t, W2t);
  mega_kernel<<<dim3(B + NCONS), dim3(512), 0, stream>>>(
      x, pos, W1t, W2t, b1, b2, Wlin, blin, idx, progress, pos4, xout, pout);
}

// Round 13
// 966.040 us; speedup vs baseline: 1.0950x; 1.0006x over previous
//
#include <hip/hip_runtime.h>
#include <hip/hip_bf16.h>

constexpr int B    = 16;
constexpr int N    = 4096;
constexpr int CIN  = 64;
constexpr int COUT = 128;
constexpr int M    = 1024;
constexpr int K    = 32;

constexpr int K1  = 96;   // layer-1 MFMA K: 64 x + 3 rel + 29 zero pad
constexpr int LDH = 136;  // A2 row stride (pad +8)

typedef __attribute__((ext_vector_type(8))) short short8;
typedef __attribute__((ext_vector_type(4))) float f32x4;
typedef __attribute__((ext_vector_type(2))) float f32x2;

// RNE float->bf16 (finite values)
static __device__ __forceinline__ unsigned short f2bf(float f) {
  unsigned u = __float_as_uint(f);
  unsigned r = (u + 0x7FFFu + ((u >> 16) & 1u)) >> 16;
  return (unsigned short)r;
}

// fast mish: v * tanh(softplus(v)) == v * s/(s+2), s = u^2+2u, u = e^v
static __device__ __forceinline__ float fast_mish(float v) {
  float u = __expf(v);
  float s = u * (u + 2.0f);
  float t = s / (s + 2.0f);
  return (v > 60.f) ? v : v * t;
}

// ---------------------------------------------------------------------------
// Wave-wide u32 max via DPP (row_shr 1/2/4/8, row_bcast 15/31, readlane 63).
// ---------------------------------------------------------------------------
template <int CTRL, int RM>
static __device__ __forceinline__ unsigned dpp_umax_step(unsigned x) {
  int o = __builtin_amdgcn_update_dpp((int)x, (int)x, CTRL, RM, 0xF, false);
  unsigned u = (unsigned)o;
  return x > u ? x : u;
}
static __device__ __forceinline__ unsigned wave_umax(unsigned x) {
  x = dpp_umax_step<0x111, 0xF>(x);  // row_shr:1
  x = dpp_umax_step<0x112, 0xF>(x);  // row_shr:2
  x = dpp_umax_step<0x114, 0xF>(x);  // row_shr:4
  x = dpp_umax_step<0x118, 0xF>(x);  // row_shr:8
  x = dpp_umax_step<0x142, 0xA>(x);  // row_bcast:15 -> rows 1,3
  x = dpp_umax_step<0x143, 0xC>(x);  // row_bcast:31 -> rows 2,3
  return (unsigned)__builtin_amdgcn_readlane((int)x, 63);
}

static __device__ __forceinline__ unsigned long long umax64(unsigned long long a,
                                                            unsigned long long b) {
  return a > b ? a : b;
}

// ---------------------------------------------------------------------------
// FPS: one block/cloud, 512 threads (8 waves = 2/SIMD), 8 pts/lane in regs as
// f32x2 pairs -> packed-FP32 distance math (IEEE-exact, half the ops).
// DPP value-umax + inv-index tie umax -> lane0 posts u64 key -> ONE barrier
// -> 8-way u64 tree -> dependent sp[n] b128 gives coords.
// Runs on 16 CUs with the rest of the chip idle (full boost clock) —
// round 10-12 proved co-running consumers drags clocks ~1.5x (DVFS) and
// slows this serial loop more than overlap saves.
// ---------------------------------------------------------------------------
__global__ __launch_bounds__(512) void fps8_kernel(const float* __restrict__ pos,
                                                   int* __restrict__ idx_out,
                                                   float* __restrict__ pout,
                                                   float* __restrict__ pos4) {
#pragma clang fp contract(off)
  const int b   = blockIdx.x;
  const int tid = threadIdx.x;
  __shared__ float sp[N][4];
  __shared__ unsigned long long skey[2][8];
  const float* p = pos + (size_t)b * (N * 3);
  float* p4 = pos4 + (size_t)b * N * 4;

  f32x2 px2[4], py2[4], pz2[4];
  float mind[8];
#pragma unroll
  for (int j = 0; j < 8; j++) {
    const int n = tid + j * 512;
    const float x = p[3 * n + 0];
    const float y = p[3 * n + 1];
    const float z = p[3 * n + 2];
    px2[j >> 1][j & 1] = x;
    py2[j >> 1][j & 1] = y;
    pz2[j >> 1][j & 1] = z;
    mind[j] = __builtin_inff();
    f32x4 v;
    v[0] = x; v[1] = y; v[2] = z; v[3] = 0.f;
    *(f32x4*)(&sp[n][0]) = v;
    *(f32x4*)(p4 + 4 * n) = v;
  }
  float qx = p[0], qy = p[1], qz = p[2];
  if (tid == 0) {
    idx_out[b * M + 0] = 0;
    pout[(size_t)(b * M + 0) * 3 + 0] = qx;
    pout[(size_t)(b * M + 0) * 3 + 1] = qy;
    pout[(size_t)(b * M + 0) * 3 + 2] = qz;
  }
  __syncthreads();

  const int wv = tid >> 6, lane = tid & 63;
  for (int t = 1; t < M; t++) {
    const f32x2 nqx = {-qx, -qx};
    const f32x2 nqy = {-qy, -qy};
    const f32x2 nqz = {-qz, -qz};
    float bv = -1.f;
    unsigned bn = 0;
#pragma unroll
    for (int k = 0; k < 4; k++) {
      f32x2 dx = px2[k] + nqx;                    // v_pk_add_f32 (exact sub)
      f32x2 dy = py2[k] + nqy;
      f32x2 dz = pz2[k] + nqz;
      f32x2 s = (dx * dx + dy * dy) + dz * dz;    // numpy order, no fma
      const float mi0 = fminf(mind[2 * k + 0], s.x);
      mind[2 * k + 0] = mi0;
      bool c0 = mi0 > bv;   // strict >, ascending n: smallest index on ties
      bv = c0 ? mi0 : bv;
      bn = c0 ? (unsigned)(tid + (2 * k + 0) * 512) : bn;
      const float mi1 = fminf(mind[2 * k + 1], s.y);
      mind[2 * k + 1] = mi1;
      bool c1 = mi1 > bv;
      bv = c1 ? mi1 : bv;
      bn = c1 ? (unsigned)(tid + (2 * k + 1) * 512) : bn;
    }
    const unsigned vb = __float_as_uint(bv);  // nonneg floats: monotone bits
    const unsigned wb = wave_umax(vb);        // wave max value
    unsigned tk = (vb == wb) ? ~bn : 0u;
    tk = wave_umax(tk);                       // ties -> smallest n
    const int par = t & 1;
    if (lane == 0) skey[par][wv] = ((unsigned long long)wb << 32) | tk;
    __syncthreads();
    const unsigned long long k0 = skey[par][0];
    const unsigned long long k1 = skey[par][1];
    const unsigned long long k2 = skey[par][2];
    const unsigned long long k3 = skey[par][3];
    const unsigned long long k4 = skey[par][4];
    const unsigned long long k5 = skey[par][5];
    const unsigned long long k6 = skey[par][6];
    const unsigned long long k7 = skey[par][7];
    const unsigned long long bb =
        umax64(umax64(umax64(k0, k1), umax64(k2, k3)),
               umax64(umax64(k4, k5), umax64(k6, k7)));
    const unsigned n = ~(unsigned)bb;
    const f32x4 qv = *(const f32x4*)(&sp[n][0]);  // one dependent b128 read
    qx = qv[0];
    qy = qv[1];
    qz = qv[2];
    if (tid == 0) {
      idx_out[b * M + t] = (int)n;
      pout[(size_t)(b * M + t) * 3 + 0] = qx;
      pout[(size_t)(b * M + t) * 3 + 1] = qy;
      pout[(size_t)(b * M + t) * 3 + 2] = qz;
    }
  }
}

// ---------------------------------------------------------------------------
// Weight prep: W1t[n][k] = bf16(W1[k][n]) for k<67 else 0   (n<128, k<96)
//              W2t[n][k] = bf16(W2[k][n])                   (n<128, k<128)
// ---------------------------------------------------------------------------
__global__ __launch_bounds__(256) void prep_weights(const float* __restrict__ W1,
                                                    const float* __restrict__ W2,
                                                    unsigned short* __restrict__ W1t,
                                                    unsigned short* __restrict__ W2t) {
  const int n = blockIdx.x;    // 128
  const int t = threadIdx.x;   // 256
  if (t < K1) {
    W1t[n * K1 + t] = (t < 67) ? f2bf(W1[t * 128 + n]) : (unsigned short)0;
  } else if (t < K1 + 128) {
    int k = t - K1;
    W2t[n * 128 + k] = f2bf(W2[k * 128 + n]);
  }
}

// ---------------------------------------------------------------------------
// Fused KNN + MLP (proven in rounds 10-12 as mega's consumer): one wave per
// centroid, 4 waves/block (256 thr), LDS 34.8KB -> 4 blocks/CU = 4 waves/SIMD.
// KNN winners are captured directly into n0/n1 registers (no nbr buffer),
// then the barrier-free wave-private MFMA MLP runs immediately.
// ---------------------------------------------------------------------------
__global__ __launch_bounds__(256) void knnmlp_kernel(
    const float* __restrict__ x, const float* __restrict__ pos4,
    const unsigned short* __restrict__ W1t, const unsigned short* __restrict__ W2t,
    const float* __restrict__ b1, const float* __restrict__ b2,
    const float* __restrict__ Wlin, const float* __restrict__ blin,
    const int* __restrict__ idx, float* __restrict__ xout) {
  __shared__ unsigned short sA2[4][32][LDH];
  const int tid  = threadIdx.x;
  const int wv   = tid >> 6;
  const int lane = tid & 63;
  const int lrow = lane & 15;
  const int g    = lane >> 4;
  unsigned short* A2 = &sA2[wv][0][0];
  const int W = blockIdx.x * 4 + wv;   // centroid; 4 waves share one cloud
  const int b = W >> 10;

  const float* p4 = pos4 + (size_t)b * N * 4;
  const int sel = idx[W];
  const f32x4 q = *(const f32x4*)(p4 + 4 * sel);
  int n0 = 0, n1 = 0;
  {
#pragma clang fp contract(off)
    const f32x2 nqx = {-q[0], -q[0]};
    const f32x2 nqy = {-q[1], -q[1]};
    const f32x2 nqz = {-q[2], -q[2]};
    float d[64];
#pragma unroll
    for (int jj = 0; jj < 32; jj++) {
      const f32x4 v0 = *(const f32x4*)(p4 + 4 * ((2 * jj + 0) * 64 + lane));
      const f32x4 v1 = *(const f32x4*)(p4 + 4 * ((2 * jj + 1) * 64 + lane));
      f32x2 vx = {v0[0], v1[0]};
      f32x2 vy = {v0[1], v1[1]};
      f32x2 vz = {v0[2], v1[2]};
      f32x2 dx = vx + nqx;
      f32x2 dy = vy + nqy;
      f32x2 dz = vz + nqz;
      f32x2 s = (dx * dx + dy * dy) + dz * dz;  // numpy order, exact
      d[2 * jj + 0] = s.x;
      d[2 * jj + 1] = s.y;
    }
    float gv[8];
    int gj[8];
#pragma unroll
    for (int gg = 0; gg < 8; gg++) {
      gv[gg] = __builtin_inff();
      gj[gg] = 8 * gg;
#pragma unroll
      for (int e = 0; e < 8; e++) {
        const int j = 8 * gg + e;
        bool c = d[j] < gv[gg];
        gv[gg] = c ? d[j] : gv[gg];
        gj[gg] = c ? j : gj[gg];
      }
    }
    for (int r = 0; r < K; r++) {
      float bv = __builtin_inff();
      int bj = 0;
#pragma unroll
      for (int gg = 0; gg < 8; gg++) {
        bool c = gv[gg] < bv;
        bv = c ? gv[gg] : bv;
        bj = c ? gj[gg] : bj;
      }
      const unsigned bn = (unsigned)(bj * 64 + lane);
      const unsigned nb = ~__float_as_uint(bv);  // ~bits: umax -> min dist
      const unsigned wnb = wave_umax(nb);
      unsigned tk = (nb == wnb) ? (0xFFFFFFFFu - bn) : 0u;
      tk = wave_umax(tk);                        // ties -> smallest n
      const unsigned wn = 0xFFFFFFFFu - tk;      // uniform across wave
      n0 = (r == lrow) ? (int)wn : n0;           // capture for MLP
      n1 = (r == 16 + lrow) ? (int)wn : n1;
      const int wj = (int)(wn >> 6);
      const int wl = (int)(wn & 63);
      const int wg = wj >> 3;
#pragma unroll
      for (int gg = 0; gg < 8; gg++) {
        if (gg == wg) {  // scalar-uniform: only winner's group pays
#pragma unroll
          for (int e = 0; e < 8; e++) {
            if (8 * gg + e == wj) {
              if (lane == wl) d[8 * gg + e] = __builtin_inff();
            }
          }
          float nv = __builtin_inff();
          int nj = 8 * gg;
#pragma unroll
          for (int e = 0; e < 8; e++) {
            const int j = 8 * gg + e;
            bool c = d[j] < nv;
            nv = c ? d[j] : nv;
            nj = c ? j : nj;
          }
          gv[gg] = nv;
          gj[gg] = nj;
        }
      }
    }
  }

  // ---------------- MLP (barrier-free, wave-private A2) ----------------
  const float qx = q[0], qy = q[1], qz = q[2];
  short8 a0[3], a1[3];
  {
    const float* xr0 = x + ((size_t)b * N + n0) * CIN;
    const float* xr1 = x + ((size_t)b * N + n1) * CIN;
#pragma unroll
    for (int kc = 0; kc < 2; kc++) {
      const int k0 = kc * 32 + g * 8;
      f32x4 u0 = *(const f32x4*)(xr0 + k0);
      f32x4 u1 = *(const f32x4*)(xr0 + k0 + 4);
      f32x4 v0 = *(const f32x4*)(xr1 + k0);
      f32x4 v1 = *(const f32x4*)(xr1 + k0 + 4);
      short8 ha, hb;
#pragma unroll
      for (int e = 0; e < 4; e++) {
        ha[e] = (short)f2bf(u0[e]);
        ha[e + 4] = (short)f2bf(u1[e]);
        hb[e] = (short)f2bf(v0[e]);
        hb[e + 4] = (short)f2bf(v1[e]);
      }
      a0[kc] = ha;
      a1[kc] = hb;
    }
    short8 z = {};
    a0[2] = z;
    a1[2] = z;
    if (g == 0) {  // k = 64..71: {rel.x, rel.y, rel.z, 0...}
      float r0x = p4[4 * n0 + 0] - qx, r0y = p4[4 * n0 + 1] - qy, r0z = p4[4 * n0 + 2] - qz;
      float r1x = p4[4 * n1 + 0] - qx, r1y = p4[4 * n1 + 1] - qy, r1z = p4[4 * n1 + 2] - qz;
      a0[2][0] = (short)f2bf(r0x); a0[2][1] = (short)f2bf(r0y); a0[2][2] = (short)f2bf(r0z);
      a1[2][0] = (short)f2bf(r1x); a1[2][1] = (short)f2bf(r1y); a1[2][2] = (short)f2bf(r1z);
    }
  }

  // layer 1: C1[32,128] = A1 @ W1t^T, mish -> A2 (wave-private)
#pragma unroll 2
  for (int nt = 0; nt < 8; nt++) {
    const unsigned short* w1r = W1t + (size_t)(nt * 16 + lrow) * K1 + g * 8;
    f32x4 c0 = {}, c1 = {};
#pragma unroll
    for (int kc = 0; kc < 3; kc++) {
      short8 bfr = *(const short8*)(w1r + kc * 32);
      c0 = __builtin_amdgcn_mfma_f32_16x16x32_bf16(a0[kc], bfr, c0, 0, 0, 0);
      c1 = __builtin_amdgcn_mfma_f32_16x16x32_bf16(a1[kc], bfr, c1, 0, 0, 0);
    }
    const int colI = nt * 16 + lrow;
    const float bb = b1[colI];
#pragma unroll
    for (int reg = 0; reg < 4; reg++) {
      const int row = g * 4 + reg;  // C layout (m89): col=lane&15, row=(lane>>4)*4+reg
      A2[row * LDH + colI] = f2bf(fast_mish(c0[reg] + bb));
      A2[(16 + row) * LDH + colI] = f2bf(fast_mish(c1[reg] + bb));
    }
  }

  f32x4 xq[4];
  {
    const float* xs = x + ((size_t)b * N + sel) * CIN + g * 16;
#pragma unroll
    for (int v = 0; v < 4; v++) xq[v] = *(const f32x4*)(xs + 4 * v);
  }

  // layer 2 + max over 32 rows + epilogue (in-wave LDS ordering)
#pragma unroll 2
  for (int nt = 0; nt < 8; nt++) {
    const unsigned short* w2r = W2t + (size_t)(nt * 16 + lrow) * 128 + g * 8;
    f32x4 c0 = {}, c1 = {};
#pragma unroll
    for (int kc = 0; kc < 4; kc++) {
      short8 af0 = *(const short8*)(A2 + lrow * LDH + kc * 32 + g * 8);
      short8 af1 = *(const short8*)(A2 + (16 + lrow) * LDH + kc * 32 + g * 8);
      short8 bfr = *(const short8*)(w2r + kc * 32);
      c0 = __builtin_amdgcn_mfma_f32_16x16x32_bf16(af0, bfr, c0, 0, 0, 0);
      c1 = __builtin_amdgcn_mfma_f32_16x16x32_bf16(af1, bfr, c1, 0, 0, 0);
    }
    float pm = fmaxf(fmaxf(fmaxf(c0[0], c0[1]), fmaxf(c0[2], c0[3])),
                     fmaxf(fmaxf(c1[0], c1[1]), fmaxf(c1[2], c1[3])));
    pm = fmaxf(pm, __shfl_xor(pm, 16, 64));
    pm = fmaxf(pm, __shfl_xor(pm, 32, 64));  // max over all 32 rows, col j
    const int j = nt * 16 + lrow;
    float s = 0.f;
#pragma unroll
    for (int e = 0; e < 16; e++) {
      s += xq[e >> 2][e & 3] * Wlin[(g * 16 + e) * 128 + j];
    }
    s += __shfl_xor(s, 16, 64);
    s += __shfl_xor(s, 32, 64);  // full 64-k dot
    if (g == 0) {
      xout[(size_t)W * 128 + j] = pm + b2[j] + s + blin[j];
    }
  }
}

// ---------------------------------------------------------------------------
extern "C" void kernel_launch(void* const* d_in, const int* in_sizes, int n_in,
                              void* d_out, int out_size, void* d_ws, size_t ws_size,
                              hipStream_t stream) {
  const float* x    = (const float*)d_in[0];
  const float* pos  = (const float*)d_in[1];
  const float* W1   = (const float*)d_in[2];
  const float* b1   = (const float*)d_in[3];
  const float* W2   = (const float*)d_in[4];
  const float* b2   = (const float*)d_in[5];
  const float* Wlin = (const float*)d_in[6];
  const float* blin = (const float*)d_in[7];

  float* out  = (float*)d_out;                 // float32 outputs
  float* xout = out;                           // [B*M*COUT]
  float* pout = out + (size_t)B * M * COUT;    // [B*M*3]

  char* ws = (char*)d_ws;
  int* idx            = (int*)ws;                           // 64 KB
  unsigned short* W1t = (unsigned short*)(ws + 65536);      // 24 KB
  unsigned short* W2t = (unsigned short*)(ws + 90112);      // 32 KB
  float* pos4         = (float*)(ws + 122880);              // 1 MB

  prep_weights<<<dim3(128), dim3(256), 0, stream>>>(W1, W2, W1t, W2t);
  fps8_kernel<<<dim3(B), dim3(512), 0, stream>>>(pos, idx, pout, pos4);
  knnmlp_kernel<<<dim3(B * M / 4), dim3(256), 0, stream>>>(
      x, pos4, W1t, W2t, b1, b2, Wlin, blin, idx, xout);
}

// Round 14
// 935.755 us; speedup vs baseline: 1.1304x; 1.0324x over previous
//
#include <hip/hip_runtime.h>
#include <hip/hip_bf16.h>

constexpr int B    = 16;
constexpr int N    = 4096;
constexpr int CIN  = 64;
constexpr int COUT = 128;
constexpr int M    = 1024;
constexpr int K    = 32;

constexpr int K1  = 96;   // layer-1 MFMA K: 64 x + 3 rel + 29 zero pad
constexpr int LDH = 136;  // A2 row stride (pad +8)

typedef __attribute__((ext_vector_type(8))) short short8;
typedef __attribute__((ext_vector_type(4))) short short4v;
typedef __attribute__((ext_vector_type(4))) float f32x4;
typedef __attribute__((ext_vector_type(2))) float f32x2;

// RNE float->bf16 (finite values)
static __device__ __forceinline__ unsigned short f2bf(float f) {
  unsigned u = __float_as_uint(f);
  unsigned r = (u + 0x7FFFu + ((u >> 16) & 1u)) >> 16;
  return (unsigned short)r;
}

// fast mish: v * tanh(softplus(v)) == v * s/(s+2), s = u^2+2u, u = e^v
// v_rcp_f32 approx div: ~1e-7 rel error, far below bf16 rounding of the
// result; avoids the ~10-instr IEEE div expansion (no fast-math flags).
static __device__ __forceinline__ float fast_mish(float v) {
  float u = __expf(v);
  float s = u * (u + 2.0f);
  float den = s + 2.0f;
  float r;
  asm("v_rcp_f32 %0, %1" : "=v"(r) : "v"(den));
  float t = s * r;
  return (v > 60.f) ? v : v * t;
}

// ---------------------------------------------------------------------------
// Wave-wide u32 max via DPP (row_shr 1/2/4/8, row_bcast 15/31, readlane 63).
// ---------------------------------------------------------------------------
template <int CTRL, int RM>
static __device__ __forceinline__ unsigned dpp_umax_step(unsigned x) {
  int o = __builtin_amdgcn_update_dpp((int)x, (int)x, CTRL, RM, 0xF, false);
  unsigned u = (unsigned)o;
  return x > u ? x : u;
}
static __device__ __forceinline__ unsigned wave_umax(unsigned x) {
  x = dpp_umax_step<0x111, 0xF>(x);  // row_shr:1
  x = dpp_umax_step<0x112, 0xF>(x);  // row_shr:2
  x = dpp_umax_step<0x114, 0xF>(x);  // row_shr:4
  x = dpp_umax_step<0x118, 0xF>(x);  // row_shr:8
  x = dpp_umax_step<0x142, 0xA>(x);  // row_bcast:15 -> rows 1,3
  x = dpp_umax_step<0x143, 0xC>(x);  // row_bcast:31 -> rows 2,3
  return (unsigned)__builtin_amdgcn_readlane((int)x, 63);
}

static __device__ __forceinline__ unsigned long long umax64(unsigned long long a,
                                                            unsigned long long b) {
  return a > b ? a : b;
}

// ---------------------------------------------------------------------------
// FPS: unchanged from round 9/13 (674 us floor). 16 CUs, chip otherwise idle.
// ---------------------------------------------------------------------------
__global__ __launch_bounds__(512) void fps8_kernel(const float* __restrict__ pos,
                                                   int* __restrict__ idx_out,
                                                   float* __restrict__ pout,
                                                   float* __restrict__ pos4) {
#pragma clang fp contract(off)
  const int b   = blockIdx.x;
  const int tid = threadIdx.x;
  __shared__ float sp[N][4];
  __shared__ unsigned long long skey[2][8];
  const float* p = pos + (size_t)b * (N * 3);
  float* p4 = pos4 + (size_t)b * N * 4;

  f32x2 px2[4], py2[4], pz2[4];
  float mind[8];
#pragma unroll
  for (int j = 0; j < 8; j++) {
    const int n = tid + j * 512;
    const float x = p[3 * n + 0];
    const float y = p[3 * n + 1];
    const float z = p[3 * n + 2];
    px2[j >> 1][j & 1] = x;
    py2[j >> 1][j & 1] = y;
    pz2[j >> 1][j & 1] = z;
    mind[j] = __builtin_inff();
    f32x4 v;
    v[0] = x; v[1] = y; v[2] = z; v[3] = 0.f;
    *(f32x4*)(&sp[n][0]) = v;
    *(f32x4*)(p4 + 4 * n) = v;
  }
  float qx = p[0], qy = p[1], qz = p[2];
  if (tid == 0) {
    idx_out[b * M + 0] = 0;
    pout[(size_t)(b * M + 0) * 3 + 0] = qx;
    pout[(size_t)(b * M + 0) * 3 + 1] = qy;
    pout[(size_t)(b * M + 0) * 3 + 2] = qz;
  }
  __syncthreads();

  const int wv = tid >> 6, lane = tid & 63;
  for (int t = 1; t < M; t++) {
    const f32x2 nqx = {-qx, -qx};
    const f32x2 nqy = {-qy, -qy};
    const f32x2 nqz = {-qz, -qz};
    float bv = -1.f;
    unsigned bn = 0;
#pragma unroll
    for (int k = 0; k < 4; k++) {
      f32x2 dx = px2[k] + nqx;                    // v_pk_add_f32 (exact sub)
      f32x2 dy = py2[k] + nqy;
      f32x2 dz = pz2[k] + nqz;
      f32x2 s = (dx * dx + dy * dy) + dz * dz;    // numpy order, no fma
      const float mi0 = fminf(mind[2 * k + 0], s.x);
      mind[2 * k + 0] = mi0;
      bool c0 = mi0 > bv;   // strict >, ascending n: smallest index on ties
      bv = c0 ? mi0 : bv;
      bn = c0 ? (unsigned)(tid + (2 * k + 0) * 512) : bn;
      const float mi1 = fminf(mind[2 * k + 1], s.y);
      mind[2 * k + 1] = mi1;
      bool c1 = mi1 > bv;
      bv = c1 ? mi1 : bv;
      bn = c1 ? (unsigned)(tid + (2 * k + 1) * 512) : bn;
    }
    const unsigned vb = __float_as_uint(bv);  // nonneg floats: monotone bits
    const unsigned wb = wave_umax(vb);        // wave max value
    unsigned tk = (vb == wb) ? ~bn : 0u;
    tk = wave_umax(tk);                       // ties -> smallest n
    const int par = t & 1;
    if (lane == 0) skey[par][wv] = ((unsigned long long)wb << 32) | tk;
    __syncthreads();
    const unsigned long long k0 = skey[par][0];
    const unsigned long long k1 = skey[par][1];
    const unsigned long long k2 = skey[par][2];
    const unsigned long long k3 = skey[par][3];
    const unsigned long long k4 = skey[par][4];
    const unsigned long long k5 = skey[par][5];
    const unsigned long long k6 = skey[par][6];
    const unsigned long long k7 = skey[par][7];
    const unsigned long long bb =
        umax64(umax64(umax64(k0, k1), umax64(k2, k3)),
               umax64(umax64(k4, k5), umax64(k6, k7)));
    const unsigned n = ~(unsigned)bb;
    const f32x4 qv = *(const f32x4*)(&sp[n][0]);  // one dependent b128 read
    qx = qv[0];
    qy = qv[1];
    qz = qv[2];
    if (tid == 0) {
      idx_out[b * M + t] = (int)n;
      pout[(size_t)(b * M + t) * 3 + 0] = qx;
      pout[(size_t)(b * M + t) * 3 + 1] = qy;
      pout[(size_t)(b * M + t) * 3 + 2] = qz;
    }
  }
}

// ---------------------------------------------------------------------------
// Weight prep: W1t[n][k] = bf16(W1[k][n]) for k<67 else 0   (n<128, k<96)
//              W2t[n][k] = bf16(W2[k][n])                   (n<128, k<128)
// ---------------------------------------------------------------------------
__global__ __launch_bounds__(256) void prep_weights(const float* __restrict__ W1,
                                                    const float* __restrict__ W2,
                                                    unsigned short* __restrict__ W1t,
                                                    unsigned short* __restrict__ W2t) {
  const int n = blockIdx.x;    // 128
  const int t = threadIdx.x;   // 256
  if (t < K1) {
    W1t[n * K1 + t] = (t < 67) ? f2bf(W1[t * 128 + n]) : (unsigned short)0;
  } else if (t < K1 + 128) {
    int k = t - K1;
    W2t[n * 128 + k] = f2bf(W2[k * 128 + n]);
  }
}

// ---------------------------------------------------------------------------
// KNN v6: 512 threads = 8 waves = 8 same-cloud centroids per block.
// pos4 staged ONCE into LDS (64KB) -> d-init reads LDS, not L2 (8x less L2
// traffic: 1.07GB -> 134MB aggregate). Selection rounds identical to knn5.
// ---------------------------------------------------------------------------
__global__ __launch_bounds__(512) void knn6_kernel(const float* __restrict__ pos4,
                                                   const int* __restrict__ idx,
                                                   int* __restrict__ nbr) {
#pragma clang fp contract(off)
  __shared__ float sp4[N * 4];  // 64 KB
  const int tid  = threadIdx.x;
  const int wv   = tid >> 6;
  const int lane = tid & 63;
  const int cent = blockIdx.x * 8 + wv;   // 8 cents share one cloud
  const int b = cent >> 10;
  const float* p4 = pos4 + (size_t)b * N * 4;
  for (int i = tid; i < N; i += 512) {
    *(f32x4*)(sp4 + 4 * i) = *(const f32x4*)(p4 + 4 * i);
  }
  __syncthreads();

  const int sel = idx[cent];
  const f32x4 q = *(const f32x4*)(sp4 + 4 * sel);
  const f32x2 nqx = {-q[0], -q[0]};
  const f32x2 nqy = {-q[1], -q[1]};
  const f32x2 nqz = {-q[2], -q[2]};

  float d[64];
#pragma unroll
  for (int jj = 0; jj < 32; jj++) {
    const f32x4 v0 = *(const f32x4*)(sp4 + 4 * ((2 * jj + 0) * 64 + lane));
    const f32x4 v1 = *(const f32x4*)(sp4 + 4 * ((2 * jj + 1) * 64 + lane));
    f32x2 vx = {v0[0], v1[0]};
    f32x2 vy = {v0[1], v1[1]};
    f32x2 vz = {v0[2], v1[2]};
    f32x2 dx = vx + nqx;
    f32x2 dy = vy + nqy;
    f32x2 dz = vz + nqz;
    f32x2 s = (dx * dx + dy * dy) + dz * dz;  // numpy order, exact
    d[2 * jj + 0] = s.x;
    d[2 * jj + 1] = s.y;
  }
  float gv[8];
  int gj[8];
#pragma unroll
  for (int g = 0; g < 8; g++) {
    gv[g] = __builtin_inff();
    gj[g] = 8 * g;
#pragma unroll
    for (int e = 0; e < 8; e++) {
      const int j = 8 * g + e;
      bool c = d[j] < gv[g];  // strict: ascending j keeps smallest on ties
      gv[g] = c ? d[j] : gv[g];
      gj[g] = c ? j : gj[g];
    }
  }

  int* out = nbr + (size_t)cent * K;
  for (int r = 0; r < K; r++) {
    float bv = __builtin_inff();
    int bj = 0;
#pragma unroll
    for (int g = 0; g < 8; g++) {
      bool c = gv[g] < bv;
      bv = c ? gv[g] : bv;
      bj = c ? gj[g] : bj;
    }
    const unsigned bn = (unsigned)(bj * 64 + lane);
    const unsigned nb = ~__float_as_uint(bv);  // ~bits: umax -> min distance
    const unsigned wnb = wave_umax(nb);
    unsigned tk = (nb == wnb) ? (0xFFFFFFFFu - bn) : 0u;
    tk = wave_umax(tk);                        // ties -> smallest global n
    const unsigned wn = 0xFFFFFFFFu - tk;      // uniform across wave
    if (lane == 0) out[r] = (int)wn;

    const int wj = (int)(wn >> 6);
    const int wl = (int)(wn & 63);
    const int wg = wj >> 3;
#pragma unroll
    for (int g = 0; g < 8; g++) {
      if (g == wg) {  // scalar-uniform: only winner's group pays
#pragma unroll
        for (int e = 0; e < 8; e++) {
          if (8 * g + e == wj) {
            if (lane == wl) d[8 * g + e] = __builtin_inff();
          }
        }
        float nv = __builtin_inff();
        int nj = 8 * g;
#pragma unroll
        for (int e = 0; e < 8; e++) {
          const int j = 8 * g + e;
          bool c = d[j] < nv;
          nv = c ? d[j] : nv;
          nj = c ? j : nj;
        }
        gv[g] = nv;
        gj[g] = nj;
      }
    }
  }
}

// ---------------------------------------------------------------------------
// MLP v4: wave-per-centroid, zero barriers, 256 thr = 4 waves = 4 cents.
// Layer-1 MFMA with SWAPPED operands: mfma(W1frag, neighbors) -> lane holds
// 4 k-CONSECUTIVE channels of one neighbor -> A2 written as packed b64
// (16 stores vs 64 b16). Layer 2 / epilogue unchanged. rcp-based mish.
// ---------------------------------------------------------------------------
__global__ __launch_bounds__(256) void mlp4_kernel(
    const float* __restrict__ x, const float* __restrict__ pos4,
    const unsigned short* __restrict__ W1t, const unsigned short* __restrict__ W2t,
    const float* __restrict__ b1, const float* __restrict__ b2,
    const float* __restrict__ Wlin, const float* __restrict__ blin,
    const int* __restrict__ idx, const int* __restrict__ nbr,
    float* __restrict__ xout) {
  __shared__ unsigned short sA2[4][32][LDH];
  const int tid  = threadIdx.x;
  const int wv   = tid >> 6;
  const int lane = tid & 63;
  const int lrow = lane & 15;
  const int g    = lane >> 4;
  unsigned short* A2 = &sA2[wv][0][0];
  const int cent = blockIdx.x * 4 + wv;
  const int b    = cent >> 10;
  const int sel  = idx[cent];
  const float* p4 = pos4 + (size_t)b * N * 4;
  const f32x4 q = *(const f32x4*)(p4 + 4 * sel);
  const float qx = q[0], qy = q[1], qz = q[2];

  const int n0 = nbr[(size_t)cent * K + lrow];
  const int n1 = nbr[(size_t)cent * K + 16 + lrow];

  // ---- build neighbor (B-operand) fragments in registers ----
  short8 a0[3], a1[3];
  {
    const float* xr0 = x + ((size_t)b * N + n0) * CIN;
    const float* xr1 = x + ((size_t)b * N + n1) * CIN;
#pragma unroll
    for (int kc = 0; kc < 2; kc++) {
      const int k0 = kc * 32 + g * 8;
      f32x4 u0 = *(const f32x4*)(xr0 + k0);
      f32x4 u1 = *(const f32x4*)(xr0 + k0 + 4);
      f32x4 v0 = *(const f32x4*)(xr1 + k0);
      f32x4 v1 = *(const f32x4*)(xr1 + k0 + 4);
      short8 ha, hb;
#pragma unroll
      for (int e = 0; e < 4; e++) {
        ha[e] = (short)f2bf(u0[e]);
        ha[e + 4] = (short)f2bf(u1[e]);
        hb[e] = (short)f2bf(v0[e]);
        hb[e + 4] = (short)f2bf(v1[e]);
      }
      a0[kc] = ha;
      a1[kc] = hb;
    }
    short8 z = {};
    a0[2] = z;
    a1[2] = z;
    if (g == 0) {  // k = 64..71: {rel.x, rel.y, rel.z, 0...}
      float r0x = p4[4 * n0 + 0] - qx, r0y = p4[4 * n0 + 1] - qy, r0z = p4[4 * n0 + 2] - qz;
      float r1x = p4[4 * n1 + 0] - qx, r1y = p4[4 * n1 + 1] - qy, r1z = p4[4 * n1 + 2] - qz;
      a0[2][0] = (short)f2bf(r0x); a0[2][1] = (short)f2bf(r0y); a0[2][2] = (short)f2bf(r0z);
      a1[2][0] = (short)f2bf(r1x); a1[2][1] = (short)f2bf(r1y); a1[2][2] = (short)f2bf(r1z);
    }
  }

  // ---- layer 1 (swapped): C = W1tile @ A1 -> lane: neighbor lrow (col),
  // channels nt*16+g*4+reg (rows) -> k-consecutive -> packed b64 write ----
#pragma unroll 2
  for (int nt = 0; nt < 8; nt++) {
    const unsigned short* w1r = W1t + (size_t)(nt * 16 + lrow) * K1 + g * 8;
    f32x4 c0 = {}, c1 = {};
#pragma unroll
    for (int kc = 0; kc < 3; kc++) {
      short8 afr = *(const short8*)(w1r + kc * 32);  // A = W1 channel rows
      c0 = __builtin_amdgcn_mfma_f32_16x16x32_bf16(afr, a0[kc], c0, 0, 0, 0);
      c1 = __builtin_amdgcn_mfma_f32_16x16x32_bf16(afr, a1[kc], c1, 0, 0, 0);
    }
    const int kbase = nt * 16 + g * 4;              // channel base (k of layer2)
    const f32x4 bb = *(const f32x4*)(b1 + kbase);   // per-reg channel bias
    short4v h0, h1;
#pragma unroll
    for (int reg = 0; reg < 4; reg++) {
      h0[reg] = (short)f2bf(fast_mish(c0[reg] + bb[reg]));
      h1[reg] = (short)f2bf(fast_mish(c1[reg] + bb[reg]));
    }
    *(short4v*)(A2 + lrow * LDH + kbase) = h0;         // neighbor lrow
    *(short4v*)(A2 + (16 + lrow) * LDH + kbase) = h1;  // neighbor 16+lrow
  }

  f32x4 xq[4];
  {
    const float* xs = x + ((size_t)b * N + sel) * CIN + g * 16;
#pragma unroll
    for (int v = 0; v < 4; v++) xq[v] = *(const f32x4*)(xs + 4 * v);
  }

  // ---- layer 2 + max over 32 rows + epilogue (in-wave LDS ordering) ----
#pragma unroll 2
  for (int nt = 0; nt < 8; nt++) {
    const unsigned short* w2r = W2t + (size_t)(nt * 16 + lrow) * 128 + g * 8;
    f32x4 c0 = {}, c1 = {};
#pragma unroll
    for (int kc = 0; kc < 4; kc++) {
      short8 af0 = *(const short8*)(A2 + lrow * LDH + kc * 32 + g * 8);
      short8 af1 = *(const short8*)(A2 + (16 + lrow) * LDH + kc * 32 + g * 8);
      short8 bfr = *(const short8*)(w2r + kc * 32);
      c0 = __builtin_amdgcn_mfma_f32_16x16x32_bf16(af0, bfr, c0, 0, 0, 0);
      c1 = __builtin_amdgcn_mfma_f32_16x16x32_bf16(af1, bfr, c1, 0, 0, 0);
    }
    float pm = fmaxf(fmaxf(fmaxf(c0[0], c0[1]), fmaxf(c0[2], c0[3])),
                     fmaxf(fmaxf(c1[0], c1[1]), fmaxf(c1[2], c1[3])));
    pm = fmaxf(pm, __shfl_xor(pm, 16, 64));
    pm = fmaxf(pm, __shfl_xor(pm, 32, 64));  // max over all 32 rows, col j
    const int j = nt * 16 + lrow;
    float s = 0.f;
#pragma unroll
    for (int e = 0; e < 16; e++) {
      s += xq[e >> 2][e & 3] * Wlin[(g * 16 + e) * 128 + j];
    }
    s += __shfl_xor(s, 16, 64);
    s += __shfl_xor(s, 32, 64);  // full 64-k dot
    if (g == 0) {
      xout[(size_t)cent * 128 + j] = pm + b2[j] + s + blin[j];
    }
  }
}

// ---------------------------------------------------------------------------
extern "C" void kernel_launch(void* const* d_in, const int* in_sizes, int n_in,
                              void* d_out, int out_size, void* d_ws, size_t ws_size,
                              hipStream_t stream) {
  const float* x    = (const float*)d_in[0];
  const float* pos  = (const float*)d_in[1];
  const float* W1   = (const float*)d_in[2];
  const float* b1   = (const float*)d_in[3];
  const float* W2   = (const float*)d_in[4];
  const float* b2   = (const float*)d_in[5];
  const float* Wlin = (const float*)d_in[6];
  const float* blin = (const float*)d_in[7];

  float* out  = (float*)d_out;                 // float32 outputs
  float* xout = out;                           // [B*M*COUT]
  float* pout = out + (size_t)B * M * COUT;    // [B*M*3]

  char* ws = (char*)d_ws;
  int* idx            = (int*)ws;                           // 64 KB
  int* nbr            = (int*)(ws + 65536);                 // 2 MB
  unsigned short* W1t = (unsigned short*)(ws + 65536 + 2097152);          // 24 KB
  unsigned short* W2t = (unsigned short*)(ws + 65536 + 2097152 + 24576);  // 32 KB
  float* pos4         = (float*)(ws + 65536 + 2097152 + 24576 + 32768);   // 1 MB

  prep_weights<<<dim3(128), dim3(256), 0, stream>>>(W1, W2, W1t, W2t);
  fps8_kernel<<<dim3(B), dim3(512), 0, stream>>>(pos, idx, pout, pos4);
  knn6_kernel<<<dim3(B * M / 8), dim3(512), 0, stream>>>(pos4, idx, nbr);
  mlp4_kernel<<<dim3(B * M / 4), dim3(256), 0, stream>>>(
      x, pos4, W1t, W2t, b1, b2, Wlin, blin, idx, nbr, xout);
}